// Round 1
// 2236.268 us; speedup vs baseline: 1.4365x; 1.4365x over previous
//
#include <hip/hip_runtime.h>

#define TOK 4096
#define SEQ 512
#define BATCH 8
#define DIM 512
#define NHEAD 8
#define DK 64
#define FFD 2048

typedef unsigned short u16;
typedef float floatx4 __attribute__((ext_vector_type(4)));
typedef short shortx8 __attribute__((ext_vector_type(8)));

__device__ __forceinline__ u16 bfh(float f) {
    union { float f; unsigned u; } x; x.f = f;
    return (u16)((x.u + 0x7fffu + ((x.u >> 16) & 1u)) >> 16);
}
__device__ __forceinline__ float bff(u16 h) {
    union { unsigned u; float f; } x; x.u = (unsigned)h << 16; return x.f;
}
// truncation-based hi/lo split: residual ~2^-16 relative, plenty for 3-term mfma
__device__ __forceinline__ void bfsplit(float v, u16& h, u16& l) {
    union { float f; unsigned u; } x; x.f = v;
    union { unsigned u; float f; } hb; hb.u = x.u & 0xffff0000u;
    float rem = v - hb.f;
    union { float f; unsigned u; } rr; rr.f = rem;
    h = (u16)(x.u >> 16);
    l = (u16)(rr.u >> 16);
}
__device__ __forceinline__ float wave_max(float v) {
    #pragma unroll
    for (int off = 32; off; off >>= 1) v = fmaxf(v, __shfl_xor(v, off, 64));
    return v;
}
__device__ __forceinline__ float wave_sum(float v) {
    #pragma unroll
    for (int off = 32; off; off >>= 1) v += __shfl_xor(v, off, 64);
    return v;
}

// sentinel: ws too small
__global__ void VAKT_52226802319686_kernel(float* out, int n) {
    int i = blockIdx.x * 256 + threadIdx.x;
    if (i < n) out[i] = 524288.f;
}

__global__ void embed_r11(const int* cd, const int* cad, const float* cemb,
                          const float* caemb, float* x0, float* y) {
    int tok = blockIdx.x;
    int idx = cd[tok];
    int resp = (cad[tok] - idx) / 1000;
    for (int d = threadIdx.x; d < DIM; d += 256) {
        float e = cemb[(size_t)idx * DIM + d];
        x0[(size_t)tok * DIM + d] = e;
        y[(size_t)tok * DIM + d] = e + caemb[resp * DIM + d];
    }
}

__global__ void concat_r11(const float* X, const float* X0, float* H) {
    int tok = blockIdx.x;
    for (int d = threadIdx.x; d < 2 * DIM; d += 256) {
        H[(size_t)tok * (2 * DIM) + d] =
            (d < DIM) ? X[(size_t)tok * DIM + d] : X0[(size_t)tok * DIM + (d - DIM)];
    }
}

__global__ void add_ln_r11(const float* X, const float* Dl, const float* sc,
                           const float* bi, float* O) {
    int lane = threadIdx.x & 63, w = threadIdx.x >> 6;
    size_t row = (size_t)blockIdx.x * 4 + w;
    const float* xr = X + row * DIM;
    const float* dr = Dl + row * DIM;
    float v[8]; float sum = 0.f, sq = 0.f;
    for (int i = 0; i < 8; i++) {
        int d = i * 64 + lane;
        float t = xr[d] + dr[d];
        v[i] = t; sum += t; sq += t * t;
    }
    sum = wave_sum(sum); sq = wave_sum(sq);
    float mean = sum * (1.0f / 512.0f);
    float var = sq * (1.0f / 512.0f) - mean * mean;
    float rstd = rsqrtf(var + 1e-5f);
    float* orow = O + row * DIM;
    for (int i = 0; i < 8; i++) {
        int d = i * 64 + lane;
        orow[d] = (v[i] - mean) * rstd * sc[d] + bi[d];
    }
}

// weights W[K][N] fp32 -> Bt hi/lo u16 [Npad][K] (transposed + bf16-split)
__global__ __launch_bounds__(256) void wsplit(const float* W, u16* Bh, u16* Bl,
                                              int N, int K) {
    __shared__ float T[64][65];
    int t = threadIdx.x;
    int k0 = blockIdx.x * 64, n0 = blockIdx.y * 64;
    for (int i = 0; i < 16; i++) {
        int idx = i * 256 + t;
        int kr = idx >> 6, nc = idx & 63;
        int gn = n0 + nc;
        T[kr][nc] = (gn < N) ? W[(size_t)(k0 + kr) * N + gn] : 0.f;
    }
    __syncthreads();
    for (int i = 0; i < 16; i++) {
        int idx = i * 256 + t;
        int nr = idx >> 6, kc = idx & 63;
        float v = T[kc][nr];
        u16 h = bfh(v);
        float rem = v - bff(h);
        size_t o = (size_t)(n0 + nr) * K + k0 + kc;
        Bh[o] = h; Bl[o] = bfh(rem);
    }
}

// C[4096,N] = A[4096,K] @ Bt^T + bias. A fp32 (split on the fly), Bt pre-split u16 [*, Krow].
// mode: 0 = bias, 1 = bias+relu, 2 = accumulate into C.
__global__ __launch_bounds__(256) void gemm_mf(const float* A, const u16* Bth, const u16* Btl,
                                               int Krow, int koff, const float* bias,
                                               float* C, int N, int K, int mode) {
    __shared__ u16 Ah[64][40], Al[64][40];
    const int t = threadIdx.x;
    const int lane = t & 63, w = t >> 6;
    const int l16 = lane & 15, quad = lane >> 4;
    const int bm0 = blockIdx.y * 64, bn0 = blockIdx.x * 64;
    const int wm = (w & 1) * 32, wn = (w >> 1) * 32;
    const int ar = t >> 2, ac = (t & 3) * 8;

    floatx4 acc[2][2];
    #pragma unroll
    for (int mi = 0; mi < 2; mi++)
        #pragma unroll
        for (int ni = 0; ni < 2; ni++) acc[mi][ni] = (floatx4){0.f, 0.f, 0.f, 0.f};

    for (int k0 = 0; k0 < K; k0 += 32) {
        __syncthreads();
        {
            const float* src = A + (size_t)(bm0 + ar) * K + k0 + ac;
            float4 v0 = ((const float4*)src)[0];
            float4 v1 = ((const float4*)src)[1];
            float vv[8] = {v0.x, v0.y, v0.z, v0.w, v1.x, v1.y, v1.z, v1.w};
            unsigned hp[4], lp[4];
            #pragma unroll
            for (int i = 0; i < 4; i++) {
                u16 h0 = bfh(vv[2*i]),   l0 = bfh(vv[2*i]   - bff(bfh(vv[2*i])));
                u16 h1 = bfh(vv[2*i+1]), l1 = bfh(vv[2*i+1] - bff(bfh(vv[2*i+1])));
                hp[i] = (unsigned)h0 | ((unsigned)h1 << 16);
                lp[i] = (unsigned)l0 | ((unsigned)l1 << 16);
            }
            *(uint4*)&Ah[ar][ac] = make_uint4(hp[0], hp[1], hp[2], hp[3]);
            *(uint4*)&Al[ar][ac] = make_uint4(lp[0], lp[1], lp[2], lp[3]);
        }
        __syncthreads();
        shortx8 ahf[2], alf[2], bhf[2], blf[2];
        #pragma unroll
        for (int mi = 0; mi < 2; mi++) {
            ahf[mi] = *(const shortx8*)&Ah[wm + mi * 16 + l16][quad * 8];
            alf[mi] = *(const shortx8*)&Al[wm + mi * 16 + l16][quad * 8];
        }
        #pragma unroll
        for (int ni = 0; ni < 2; ni++) {
            size_t o = (size_t)(bn0 + wn + ni * 16 + l16) * Krow + koff + k0 + quad * 8;
            bhf[ni] = *(const shortx8*)(Bth + o);
            blf[ni] = *(const shortx8*)(Btl + o);
        }
        #pragma unroll
        for (int mi = 0; mi < 2; mi++)
            #pragma unroll
            for (int ni = 0; ni < 2; ni++) {
                acc[mi][ni] = __builtin_amdgcn_mfma_f32_16x16x32_bf16(ahf[mi], bhf[ni], acc[mi][ni], 0, 0, 0);
                acc[mi][ni] = __builtin_amdgcn_mfma_f32_16x16x32_bf16(ahf[mi], blf[ni], acc[mi][ni], 0, 0, 0);
                acc[mi][ni] = __builtin_amdgcn_mfma_f32_16x16x32_bf16(alf[mi], bhf[ni], acc[mi][ni], 0, 0, 0);
            }
    }
    #pragma unroll
    for (int ni = 0; ni < 2; ni++) {
        int col = bn0 + wn + ni * 16 + l16;
        if (col < N) {
            float bv = (mode == 2) ? 0.f : bias[col];
            #pragma unroll
            for (int mi = 0; mi < 2; mi++) {
                #pragma unroll
                for (int r = 0; r < 4; r++) {
                    int row = bm0 + wm + mi * 16 + quad * 4 + r;
                    size_t o = (size_t)row * N + col;
                    float v = acc[mi][ni][r] + bv;
                    if (mode == 1 && v < 0.f) v = 0.f;
                    if (mode == 2) v += C[o];
                    C[o] = v;
                }
            }
        }
    }
}

// elementwise hi/lo bf16 split of K projection: [4096,512] f32 -> two u16 planes
__global__ __launch_bounds__(256) void ksplit(const float* __restrict__ src,
                                              u16* __restrict__ dh, u16* __restrict__ dl) {
    size_t i = ((size_t)blockIdx.x * 256 + threadIdx.x) * 4;
    float4 v = *(const float4*)(src + i);
    u16 h0, h1, h2, h3, l0, l1, l2, l3;
    bfsplit(v.x, h0, l0); bfsplit(v.y, h1, l1);
    bfsplit(v.z, h2, l2); bfsplit(v.w, h3, l3);
    ushort4 hv = {h0, h1, h2, h3}, lv = {l0, l1, l2, l3};
    *(ushort4*)(dh + i) = hv;
    *(ushort4*)(dl + i) = lv;
}

// per-head transpose + hi/lo split of V projection:
// vb [4096,512] f32 -> Vt [b*8+h][64 d][512 s] u16 (hi plane, lo plane)
__global__ __launch_bounds__(256) void vtsplit(const float* __restrict__ vb,
                                               u16* __restrict__ dh, u16* __restrict__ dl) {
    __shared__ float tile[64][66];
    const int t = threadIdx.x;
    const int s0 = blockIdx.x * 64;
    const int bh = blockIdx.y;
    const int b = bh >> 3, h = bh & 7;
    const int r = t >> 2, seg = t & 3;
    {
        const float* src = vb + (size_t)(b * SEQ + s0 + r) * DIM + h * 64 + seg * 16;
        #pragma unroll
        for (int j = 0; j < 4; ++j) {
            float4 v = *(const float4*)(src + j * 4);
            tile[r][seg * 16 + j * 4 + 0] = v.x;
            tile[r][seg * 16 + j * 4 + 1] = v.y;
            tile[r][seg * 16 + j * 4 + 2] = v.z;
            tile[r][seg * 16 + j * 4 + 3] = v.w;
        }
    }
    __syncthreads();
    union { u16 e[16]; uint4 q[2]; } hb, lb;
    #pragma unroll
    for (int j = 0; j < 16; ++j) bfsplit(tile[seg * 16 + j][r], hb.e[j], lb.e[j]);
    size_t dst = ((size_t)bh * 64 + r) * SEQ + s0 + seg * 16;
    *(uint4*)(dh + dst)     = hb.q[0];
    *(uint4*)(dh + dst + 8) = hb.q[1];
    *(uint4*)(dl + dst)     = lb.q[0];
    *(uint4*)(dl + dst + 8) = lb.q[1];
}

// MFMA attention. One block = 64 query rows of one (b,h); 4 waves x 16 rows.
// Swapped QK^T (scoresT = mfma(K,Q)) so each lane owns one q-row -> softmax,
// cumsum distance-decay, and second softmax are register-resident.
// All matmuls use 3-term hi/lo bf16 split (~fp32 accuracy).
__global__ __launch_bounds__(256, 2) void attn_mf(
    const float* __restrict__ Q,
    const u16* __restrict__ Kh, const u16* __restrict__ Kl,
    const u16* __restrict__ Vth, const u16* __restrict__ Vtl,
    const float* __restrict__ gam, float* __restrict__ O, int m0) {
    __shared__ __align__(16) u16 KV[2][64][72];       // K rows (ph1) / V^T rows (ph3)
    __shared__ __align__(16) u16 PB[4][2][16][72];    // per-wave P repack buffer
    const int t = threadIdx.x;
    const int lane = t & 63, w = t >> 6;
    const int l16 = lane & 15, quad = lane >> 4;
    const int chunk = 7 - (int)blockIdx.x;            // heavy blocks dispatch first
    const int h = blockIdx.y, b = blockIdx.z;
    const int bS = b * SEQ;
    const int bh = b * NHEAD + h;
    const int nch = chunk + 1, nkt = nch * 4;
    const int qrow0 = chunk * 64 + w * 16;
    const int qrow = qrow0 + l16;
    const int kmax = qrow - m0;
    const int srow = t >> 2, sseg = t & 3;

    float g = gam[h];
    float gamma = -((g > 20.f) ? g : log1pf(__expf(g)));

    // Q fragments, pre-scaled by 1/sqrt(dk)=0.125
    union QU { shortx8 v; u16 e[8]; };
    QU qh[2], ql[2];
    {
        const float* qp = Q + (size_t)(bS + qrow) * DIM + h * 64;
        #pragma unroll
        for (int ks = 0; ks < 2; ++ks) {
            float4 v0 = *(const float4*)(qp + ks * 32 + quad * 8);
            float4 v1 = *(const float4*)(qp + ks * 32 + quad * 8 + 4);
            float vv[8] = {v0.x, v0.y, v0.z, v0.w, v1.x, v1.y, v1.z, v1.w};
            #pragma unroll
            for (int j = 0; j < 8; ++j) bfsplit(vv[j] * 0.125f, qh[ks].e[j], ql[ks].e[j]);
        }
    }

    floatx4 s[32];   // scoresT: lane l16 = q-row, reg (quad*4+r within tile) = key
    #pragma unroll
    for (int i = 0; i < 32; ++i) s[i] = (floatx4){0.f, 0.f, 0.f, 0.f};

    // ---- Phase 1: scoresT = K . Q^T over causal key chunks ----
    #pragma unroll
    for (int c = 0; c < 8; ++c) {
        if (c < nch) {
            __syncthreads();
            {
                size_t src = (size_t)(bS + c * 64 + srow) * DIM + h * 64 + sseg * 16;
                *(uint4*)&KV[0][srow][sseg * 16]     = *(const uint4*)(Kh + src);
                *(uint4*)&KV[0][srow][sseg * 16 + 8] = *(const uint4*)(Kh + src + 8);
                *(uint4*)&KV[1][srow][sseg * 16]     = *(const uint4*)(Kl + src);
                *(uint4*)&KV[1][srow][sseg * 16 + 8] = *(const uint4*)(Kl + src + 8);
            }
            __syncthreads();
            #pragma unroll
            for (int kt = 0; kt < 4; ++kt) {
                shortx8 kh0 = *(const shortx8*)&KV[0][kt * 16 + l16][quad * 8];
                shortx8 kh1 = *(const shortx8*)&KV[0][kt * 16 + l16][32 + quad * 8];
                shortx8 kl0 = *(const shortx8*)&KV[1][kt * 16 + l16][quad * 8];
                shortx8 kl1 = *(const shortx8*)&KV[1][kt * 16 + l16][32 + quad * 8];
                floatx4 a = s[c * 4 + kt];
                a = __builtin_amdgcn_mfma_f32_16x16x32_bf16(kh0, qh[0].v, a, 0, 0, 0);
                a = __builtin_amdgcn_mfma_f32_16x16x32_bf16(kh1, qh[1].v, a, 0, 0, 0);
                a = __builtin_amdgcn_mfma_f32_16x16x32_bf16(kh0, ql[0].v, a, 0, 0, 0);
                a = __builtin_amdgcn_mfma_f32_16x16x32_bf16(kh1, ql[1].v, a, 0, 0, 0);
                a = __builtin_amdgcn_mfma_f32_16x16x32_bf16(kl0, qh[0].v, a, 0, 0, 0);
                a = __builtin_amdgcn_mfma_f32_16x16x32_bf16(kl1, qh[1].v, a, 0, 0, 0);
                s[c * 4 + kt] = a;
            }
        }
    }

    // ---- Phase 2: softmax -> cumsum decay -> second softmax (registers) ----
    float m1 = -1e30f;
    #pragma unroll
    for (int kt = 0; kt < 32; ++kt) {
        if (kt < nkt) {
            #pragma unroll
            for (int r = 0; r < 4; ++r) {
                int key = kt * 16 + quad * 4 + r;
                float sv = (key <= kmax) ? s[kt][r] : -1e30f;
                s[kt][r] = sv;
                m1 = fmaxf(m1, sv);
            }
        }
    }
    m1 = fmaxf(m1, __shfl_xor(m1, 16, 64));
    m1 = fmaxf(m1, __shfl_xor(m1, 32, 64));

    float sum1 = 0.f;
    #pragma unroll
    for (int kt = 0; kt < 32; ++kt) {
        if (kt < nkt) {
            #pragma unroll
            for (int r = 0; r < 4; ++r) sum1 += __expf(s[kt][r] - m1);
        }
    }
    sum1 += __shfl_xor(sum1, 16, 64);
    sum1 += __shfl_xor(sum1, 32, 64);
    float inv1 = 1.f / sum1;

    float carry = 0.f, m2 = -1e30f;
    #pragma unroll
    for (int kt = 0; kt < 32; ++kt) {
        if (kt < nkt) {
            float e0 = __expf(s[kt][0] - m1);
            float e1 = __expf(s[kt][1] - m1);
            float e2 = __expf(s[kt][2] - m1);
            float e3 = __expf(s[kt][3] - m1);
            float c0 = e0, c1 = c0 + e1, c2 = c1 + e2, c3 = c2 + e3;
            float q0 = __shfl(c3, l16, 64);
            float q1 = __shfl(c3, l16 + 16, 64);
            float q2 = __shfl(c3, l16 + 32, 64);
            float q3 = __shfl(c3, l16 + 48, 64);
            float excl = carry;
            if (quad > 0) excl += q0;
            if (quad > 1) excl += q1;
            if (quad > 2) excl += q2;
            carry += q0 + q1 + q2 + q3;
            float cc[4] = {c0, c1, c2, c3};
            #pragma unroll
            for (int r = 0; r < 4; ++r) {
                int key = kt * 16 + quad * 4 + r;
                float distcum = (excl + cc[r]) * inv1;
                float rem = fmaxf(1.f - distcum, 0.f);
                float prod = fmaxf(rem * (float)(qrow - key), 0.f);
                float te = fmaxf(__expf(sqrtf(prod) * gamma), 1e-5f);
                float sv2 = s[kt][r] * te;
                s[kt][r] = sv2;
                m2 = fmaxf(m2, sv2);
            }
        }
    }
    m2 = fmaxf(m2, __shfl_xor(m2, 16, 64));
    m2 = fmaxf(m2, __shfl_xor(m2, 32, 64));

    float sum2 = 0.f;
    #pragma unroll
    for (int kt = 0; kt < 32; ++kt) {
        if (kt < nkt) {
            #pragma unroll
            for (int r = 0; r < 4; ++r) {
                float p = __expf(s[kt][r] - m2);
                s[kt][r] = p;
                sum2 += p;
            }
        }
    }
    sum2 += __shfl_xor(sum2, 16, 64);
    sum2 += __shfl_xor(sum2, 32, 64);
    float inv2 = 1.f / sum2;

    // ---- Phase 3: O = P . V over causal key chunks ----
    floatx4 o[4];
    #pragma unroll
    for (int i = 0; i < 4; ++i) o[i] = (floatx4){0.f, 0.f, 0.f, 0.f};

    #pragma unroll
    for (int c = 0; c < 8; ++c) {
        if (c < nch) {
            __syncthreads();
            {
                size_t src = ((size_t)bh * 64 + srow) * SEQ + c * 64 + sseg * 16;
                *(uint4*)&KV[0][srow][sseg * 16]     = *(const uint4*)(Vth + src);
                *(uint4*)&KV[0][srow][sseg * 16 + 8] = *(const uint4*)(Vth + src + 8);
                *(uint4*)&KV[1][srow][sseg * 16]     = *(const uint4*)(Vtl + src);
                *(uint4*)&KV[1][srow][sseg * 16 + 8] = *(const uint4*)(Vtl + src + 8);
            }
            // repack this chunk of P into A-fragment layout (per-wave LDS)
            #pragma unroll
            for (int kt = 0; kt < 4; ++kt) {
                floatx4 pv = s[c * 4 + kt];
                u16 hh[4], ll[4];
                #pragma unroll
                for (int r = 0; r < 4; ++r) bfsplit(pv[r] * inv2, hh[r], ll[r]);
                uint2 hw, lw;
                hw.x = (unsigned)hh[0] | ((unsigned)hh[1] << 16);
                hw.y = (unsigned)hh[2] | ((unsigned)hh[3] << 16);
                lw.x = (unsigned)ll[0] | ((unsigned)ll[1] << 16);
                lw.y = (unsigned)ll[2] | ((unsigned)ll[3] << 16);
                *(uint2*)&PB[w][0][l16][kt * 16 + quad * 4] = hw;
                *(uint2*)&PB[w][1][l16][kt * 16 + quad * 4] = lw;
            }
            __syncthreads();
            shortx8 ph0 = *(const shortx8*)&PB[w][0][l16][quad * 8];
            shortx8 ph1 = *(const shortx8*)&PB[w][0][l16][32 + quad * 8];
            shortx8 pl0 = *(const shortx8*)&PB[w][1][l16][quad * 8];
            shortx8 pl1 = *(const shortx8*)&PB[w][1][l16][32 + quad * 8];
            #pragma unroll
            for (int dt = 0; dt < 4; ++dt) {
                shortx8 vh0 = *(const shortx8*)&KV[0][dt * 16 + l16][quad * 8];
                shortx8 vh1 = *(const shortx8*)&KV[0][dt * 16 + l16][32 + quad * 8];
                shortx8 vl0 = *(const shortx8*)&KV[1][dt * 16 + l16][quad * 8];
                shortx8 vl1 = *(const shortx8*)&KV[1][dt * 16 + l16][32 + quad * 8];
                floatx4 a = o[dt];
                a = __builtin_amdgcn_mfma_f32_16x16x32_bf16(ph0, vh0, a, 0, 0, 0);
                a = __builtin_amdgcn_mfma_f32_16x16x32_bf16(ph1, vh1, a, 0, 0, 0);
                a = __builtin_amdgcn_mfma_f32_16x16x32_bf16(ph0, vl0, a, 0, 0, 0);
                a = __builtin_amdgcn_mfma_f32_16x16x32_bf16(ph1, vl1, a, 0, 0, 0);
                a = __builtin_amdgcn_mfma_f32_16x16x32_bf16(pl0, vh0, a, 0, 0, 0);
                a = __builtin_amdgcn_mfma_f32_16x16x32_bf16(pl1, vh1, a, 0, 0, 0);
                o[dt] = a;
            }
        }
    }

    #pragma unroll
    for (int dt = 0; dt < 4; ++dt) {
        #pragma unroll
        for (int r = 0; r < 4; ++r) {
            int row = qrow0 + quad * 4 + r;
            float v = o[dt][r];
            if (m0 && row == 0) v = 0.f;
            O[(size_t)(bS + row) * DIM + h * 64 + dt * 16 + l16] = v;
        }
    }
}

static void run_wsplit(const float* W, u16* Bh, u16* Bl, int N, int K, int Npad,
                       hipStream_t stream) {
    wsplit<<<dim3(K / 64, Npad / 64), dim3(256), 0, stream>>>(W, Bh, Bl, N, K);
}
static void run_gemm(const float* A, const u16* Bth, const u16* Btl, int Krow, int koff,
                     const float* bias, float* C, int N, int K, int mode, hipStream_t stream) {
    dim3 g((N + 63) / 64, TOK / 64);
    gemm_mf<<<g, dim3(256), 0, stream>>>(A, Bth, Btl, Krow, koff, bias, C, N, K, mode);
}

extern "C" void kernel_launch(void* const* d_in, const int* in_sizes, int n_in,
                              void* d_out, int out_size, void* d_ws, size_t ws_size,
                              hipStream_t stream) {
    (void)in_sizes; (void)n_in;
    const int* c_data    = (const int*)d_in[0];
    const int* ca_data   = (const int*)d_in[1];
    const float* c_emb   = (const float*)d_in[2];
    const float* ca_emb  = (const float*)d_in[3];
    const float* Wk  = (const float*)d_in[4];
    const float* bk  = (const float*)d_in[5];
    const float* Wv  = (const float*)d_in[6];
    const float* bv  = (const float*)d_in[7];
    const float* Wo  = (const float*)d_in[8];
    const float* bo  = (const float*)d_in[9];
    const float* gammas = (const float*)d_in[10];
    const float* ln1s = (const float*)d_in[11];
    const float* ln1b = (const float*)d_in[12];
    const float* W1  = (const float*)d_in[13];
    const float* b1  = (const float*)d_in[14];
    const float* W2  = (const float*)d_in[15];
    const float* b2  = (const float*)d_in[16];
    const float* ln2s = (const float*)d_in[17];
    const float* ln2b = (const float*)d_in[18];
    const float* oW0 = (const float*)d_in[19];
    const float* ob0 = (const float*)d_in[20];
    const float* oW1 = (const float*)d_in[21];
    const float* ob1 = (const float*)d_in[22];
    const float* oW2 = (const float*)d_in[23];
    const float* ob2 = (const float*)d_in[24];

    float* out = (float*)d_out;
    const size_t MB = 1024 * 1024;
    if (ws_size < 64 * MB) {
        VAKT_52226802319686_kernel<<<dim3((out_size + 255) / 256), dim3(256), 0, stream>>>(out, out_size);
        return;
    }
    char* wsp = (char*)d_ws;
    float* x0b = (float*)(wsp);             // 0-8
    float* yb  = (float*)(wsp + 8 * MB);    // 8-16
    float* xb  = (float*)(wsp + 16 * MB);   // 16-24
    float* qb  = (float*)(wsp + 24 * MB);   // 24-32
    float* kb  = (float*)(wsp + 32 * MB);   // 32-40
    float* vb  = (float*)(wsp + 40 * MB);   // 40-48
    float* ao  = (float*)(wsp + 48 * MB);   // 48-56
    float* t1  = (float*)(wsp + 56 * MB);   // 56-64
    // Bt regions (u16 hi/lo), liveness-overlapped:
    u16* btWk_h = (u16*)(wsp + 48 * MB);  u16* btWk_l = (u16*)(wsp + 49 * MB);  // dead before attn
    u16* btWv_h = (u16*)(wsp + 50 * MB);  u16* btWv_l = (u16*)(wsp + 51 * MB);
    u16* btWo_h = (u16*)(wsp + 24 * MB);  u16* btWo_l = (u16*)(wsp + 25 * MB);  // qb dead after attn
    u16* btW1_h = (u16*)(wsp + 24 * MB);  u16* btW1_l = (u16*)(wsp + 26 * MB);  // after Wo gemm
    u16* btW2_h = (u16*)(wsp + 28 * MB);  u16* btW2_l = (u16*)(wsp + 30 * MB);
    float* ffc  = (float*)(wsp + 32 * MB);  // 32-48: FFN chunk 4096x1024 (kb,vb dead)
    // attention pre-split buffers (liveness-overlapped):
    u16* Kh_g  = (u16*)(wsp + 56 * MB);   // 56-60 (t1 region; t1 used only after attn)
    u16* Kl_g  = (u16*)(wsp + 60 * MB);   // 60-64
    u16* Vth_g = (u16*)(wsp + 32 * MB);   // 32-36 (kb region; kb consumed by ksplit first)
    u16* Vtl_g = (u16*)(wsp + 36 * MB);   // 36-40
    // head
    float* hcat = (float*)(wsp + 24 * MB);  // 24-40
    float* h1   = (float*)(wsp + 48 * MB);  // 48-56
    float* h2   = (float*)(wsp + 24 * MB);  // 24-40 (hcat dead after oW0)
    u16* btH_h  = (u16*)(wsp + 40 * MB);
    u16* btH_l  = (u16*)(wsp + 42 * MB);

    embed_r11<<<dim3(TOK), dim3(256), 0, stream>>>(c_data, ca_data, c_emb, ca_emb, x0b, yb);

    for (int li = 0; li < 6; ++li) {
        const float *query, *key, *values; float* outb; int m0; int pos;
        if (li == 0 || li == 1) { query = yb; key = x0b; values = yb; outb = yb; m0 = 0; pos = 1; }
        else if (li == 2) { query = x0b; key = x0b; values = x0b; outb = xb; m0 = 0; pos = 0; }
        else if (li == 3) { query = xb; key = xb; values = yb; outb = xb; m0 = 1; pos = 1; }
        else if (li == 4) { query = xb; key = xb; values = xb; outb = xb; m0 = 0; pos = 0; }
        else { query = xb; key = xb; values = yb; outb = xb; m0 = 1; pos = 1; }

        run_wsplit(Wk + (size_t)li * DIM * DIM, btWk_h, btWk_l, DIM, DIM, DIM, stream);
        run_wsplit(Wv + (size_t)li * DIM * DIM, btWv_h, btWv_l, DIM, DIM, DIM, stream);
        run_gemm(query, btWk_h, btWk_l, DIM, 0, bk + li * DIM, qb, DIM, DIM, 0, stream);
        const float* kb_use = qb;
        if (key != query) {
            run_gemm(key, btWk_h, btWk_l, DIM, 0, bk + li * DIM, kb, DIM, DIM, 0, stream);
            kb_use = kb;
        }
        run_gemm(values, btWv_h, btWv_l, DIM, 0, bv + li * DIM, vb, DIM, DIM, 0, stream);
        // pre-split K (hi/lo bf16) and transpose+split V per head, then MFMA attention
        ksplit<<<dim3(2048), dim3(256), 0, stream>>>(kb_use, Kh_g, Kl_g);
        vtsplit<<<dim3(8, 64), dim3(256), 0, stream>>>(vb, Vth_g, Vtl_g);
        attn_mf<<<dim3(8, NHEAD, BATCH), dim3(256), 0, stream>>>(
            qb, Kh_g, Kl_g, Vth_g, Vtl_g, gammas + li * NHEAD, ao, m0);
        run_wsplit(Wo + (size_t)li * DIM * DIM, btWo_h, btWo_l, DIM, DIM, DIM, stream);
        run_gemm(ao, btWo_h, btWo_l, DIM, 0, bo + li * DIM, t1, DIM, DIM, 0, stream);
        add_ln_r11<<<dim3(TOK / 4), dim3(256), 0, stream>>>(query, t1, ln1s + li * DIM, ln1b + li * DIM, outb);
        if (pos) {
            run_wsplit(W1 + (size_t)li * DIM * FFD, btW1_h, btW1_l, FFD, DIM, FFD, stream);
            run_wsplit(W2 + (size_t)li * FFD * DIM, btW2_h, btW2_l, DIM, FFD, DIM, stream);
            for (int c = 0; c < 2; ++c) {
                run_gemm(outb, btW1_h + (size_t)c * 1024 * DIM, btW1_l + (size_t)c * 1024 * DIM,
                         DIM, 0, b1 + li * FFD + c * 1024, ffc, 1024, DIM, 1, stream);
                run_gemm(ffc, btW2_h, btW2_l, FFD, c * 1024, b2 + li * DIM, t1,
                         DIM, 1024, (c == 0) ? 0 : 2, stream);
            }
            add_ln_r11<<<dim3(TOK / 4), dim3(256), 0, stream>>>(outb, t1, ln2s + li * DIM, ln2b + li * DIM, outb);
        }
    }

    concat_r11<<<dim3(TOK), dim3(256), 0, stream>>>(xb, x0b, hcat);
    run_wsplit(oW0, btH_h, btH_l, 512, 1024, 512, stream);
    run_gemm(hcat, btH_h, btH_l, 1024, 0, ob0, h1, 512, 1024, 1, stream);
    run_wsplit(oW1, btH_h, btH_l, 1024, 512, 1024, stream);
    run_gemm(h1, btH_h, btH_l, 512, 0, ob1, h2, 1024, 512, 1, stream);
    run_wsplit(oW2, btH_h, btH_l, 1000, 1024, 1024, stream);
    run_gemm(h2, btH_h, btH_l, 1024, 0, ob2, out, 1000, 1024, 0, stream);
}

// Round 2
// 1760.795 us; speedup vs baseline: 1.8244x; 1.2700x over previous
//
#include <hip/hip_runtime.h>

#define TOK 4096
#define SEQ 512
#define BATCH 8
#define DIM 512
#define NHEAD 8
#define DK 64
#define FFD 2048

typedef unsigned short u16;
typedef unsigned int u32;
typedef float floatx4 __attribute__((ext_vector_type(4)));
typedef short shortx8 __attribute__((ext_vector_type(8)));

// epilogue mode bits
#define EP_RELU 1
#define EP_ACC  2
#define EP_F32  4
#define EP_PL   8

__device__ __forceinline__ u16 bfh(float f) {
    union { float f; unsigned u; } x; x.f = f;
    return (u16)((x.u + 0x7fffu + ((x.u >> 16) & 1u)) >> 16);
}
__device__ __forceinline__ float bff(u16 h) {
    union { unsigned u; float f; } x; x.u = (unsigned)h << 16; return x.f;
}
// truncation-based hi/lo split: residual ~2^-16 relative
__device__ __forceinline__ void bfsplit(float v, u16& h, u16& l) {
    union { float f; unsigned u; } x; x.f = v;
    union { unsigned u; float f; } hb; hb.u = x.u & 0xffff0000u;
    float rem = v - hb.f;
    union { float f; unsigned u; } rr; rr.f = rem;
    h = (u16)(x.u >> 16);
    l = (u16)(rr.u >> 16);
}
__device__ __forceinline__ float wave_sum(float v) {
    #pragma unroll
    for (int off = 32; off; off >>= 1) v += __shfl_xor(v, off, 64);
    return v;
}

#define GLDS16(gp, lp) __builtin_amdgcn_global_load_lds( \
    (const __attribute__((address_space(1))) u32*)(const void*)(gp), \
    (__attribute__((address_space(3))) u32*)(void*)(lp), 16, 0, 0)

// sentinel: ws too small
__global__ void VAKT_52226802319686_kernel(float* out, int n) {
    int i = blockIdx.x * 256 + threadIdx.x;
    if (i < n) out[i] = 524288.f;
}

__global__ void embed_pp(const int* cd, const int* cad, const float* cemb,
                         const float* caemb, float* x0, float* y,
                         u16* x0h, u16* x0l, u16* yh, u16* yl) {
    int tok = blockIdx.x;
    int idx = cd[tok];
    int resp = (cad[tok] - idx) / 1000;
    for (int d = threadIdx.x; d < DIM; d += 256) {
        float e = cemb[(size_t)idx * DIM + d];
        float yv = e + caemb[resp * DIM + d];
        size_t o = (size_t)tok * DIM + d;
        x0[o] = e; y[o] = yv;
        u16 hh, ll;
        bfsplit(e, hh, ll);  x0h[o] = hh; x0l[o] = ll;
        bfsplit(yv, hh, ll); yh[o] = hh;  yl[o] = ll;
    }
}

__global__ void concat_pp(const float* X, const float* X0, u16* Hh, u16* Hl) {
    int tok = blockIdx.x;
    for (int d = threadIdx.x; d < 2 * DIM; d += 256) {
        float v = (d < DIM) ? X[(size_t)tok * DIM + d] : X0[(size_t)tok * DIM + d - DIM];
        u16 hh, ll; bfsplit(v, hh, ll);
        Hh[(size_t)tok * (2 * DIM) + d] = hh;
        Hl[(size_t)tok * (2 * DIM) + d] = ll;
    }
}

__global__ void add_ln_pp(const float* X, const float* Dl, const float* sc,
                          const float* bi, float* O, u16* Oh, u16* Ol) {
    int lane = threadIdx.x & 63, w = threadIdx.x >> 6;
    size_t row = (size_t)blockIdx.x * 4 + w;
    const float* xr = X + row * DIM;
    const float* dr = Dl + row * DIM;
    float v[8]; float sum = 0.f, sq = 0.f;
    for (int i = 0; i < 8; i++) {
        int d = i * 64 + lane;
        float t = xr[d] + dr[d];
        v[i] = t; sum += t; sq += t * t;
    }
    sum = wave_sum(sum); sq = wave_sum(sq);
    float mean = sum * (1.0f / 512.0f);
    float var = sq * (1.0f / 512.0f) - mean * mean;
    float rstd = rsqrtf(var + 1e-5f);
    float* orow = O + row * DIM;
    for (int i = 0; i < 8; i++) {
        int d = i * 64 + lane;
        float val = (v[i] - mean) * rstd * sc[d] + bi[d];
        orow[d] = val;
        u16 hh, ll; bfsplit(val, hh, ll);
        Oh[row * DIM + d] = hh; Ol[row * DIM + d] = ll;
    }
}

// weights W[K][N] fp32 -> Bt hi/lo u16 [Npad][K] (transposed + bf16-split)
__global__ __launch_bounds__(256) void wsplit(const float* W, u16* Bh, u16* Bl,
                                              int N, int K) {
    __shared__ float T[64][65];
    int t = threadIdx.x;
    int k0 = blockIdx.x * 64, n0 = blockIdx.y * 64;
    for (int i = 0; i < 16; i++) {
        int idx = i * 256 + t;
        int kr = idx >> 6, nc = idx & 63;
        int gn = n0 + nc;
        T[kr][nc] = (gn < N) ? W[(size_t)(k0 + kr) * N + gn] : 0.f;
    }
    __syncthreads();
    for (int i = 0; i < 16; i++) {
        int idx = i * 256 + t;
        int nr = idx >> 6, kc = idx & 63;
        float v = T[kc][nr];
        u16 h = bfh(v);
        float rem = v - bff(h);
        size_t o = (size_t)(n0 + nr) * K + k0 + kc;
        Bh[o] = h; Bl[o] = bfh(rem);
    }
}

// C[4096,N] = A @ Bt^T (+bias). A as pre-split u16 planes [4096][K] (hi,lo).
// B pre-split [Npad][Bstride] with k-window at Boff. 128x64 tile, BK=64,
// 4 waves x (64x32). global_load_lds staging with source-side XOR swizzle.
__global__ __launch_bounds__(256) void gemm_pp(
    const u16* __restrict__ Ah, const u16* __restrict__ Al,
    const u16* __restrict__ Bh, const u16* __restrict__ Bl,
    int K, int Bstride, int Boff,
    const float* __restrict__ bias, int N, int mode,
    float* __restrict__ Cf, u16* __restrict__ Ch, u16* __restrict__ Cl) {
    // layout: Ah tile [128][64] @0, Al @8192, Bh [64][64] @16384, Bl @20480 (u16 units)
    __shared__ u16 sm[24576];
    const int t = threadIdx.x;
    const int lane = t & 63, w = t >> 6;
    const int l16 = lane & 15, quad = lane >> 4;
    const int bm0 = blockIdx.y * 128, bn0 = blockIdx.x * 64;
    const int wm = (w & 1) * 64, wn = (w >> 1) * 32;

    floatx4 acc[4][2];
    #pragma unroll
    for (int mi = 0; mi < 4; mi++)
        #pragma unroll
        for (int ni = 0; ni < 2; ni++) acc[mi][ni] = (floatx4){0.f, 0.f, 0.f, 0.f};

    for (int k0 = 0; k0 < K; k0 += 64) {
        __syncthreads();
        // stage A: 2 planes x 4 rounds (wave covers 64 x 16B per round)
        #pragma unroll
        for (int p = 0; p < 2; ++p) {
            const u16* Asrc = p ? Al : Ah;
            #pragma unroll
            for (int rr = 0; rr < 4; ++rr) {
                int idx = (rr * 4 + w) * 64 + lane;       // 16B-seg index, 0..1023
                int row = idx >> 3;
                int sg = (idx & 7) ^ (row & 7);           // source-side swizzle
                const u16* gp = Asrc + (size_t)(bm0 + row) * K + k0 + sg * 8;
                u16* lp = sm + p * 8192 + (rr * 4 + w) * 512;  // wave-uniform
                GLDS16(gp, lp);
            }
        }
        // stage B: 2 planes x 2 rounds
        #pragma unroll
        for (int p = 0; p < 2; ++p) {
            const u16* Bsrc = p ? Bl : Bh;
            #pragma unroll
            for (int rr = 0; rr < 2; ++rr) {
                int idx = (rr * 4 + w) * 64 + lane;       // 0..511
                int row = idx >> 3;
                int sg = (idx & 7) ^ (row & 7);
                const u16* gp = Bsrc + (size_t)(bn0 + row) * Bstride + Boff + k0 + sg * 8;
                u16* lp = sm + 16384 + p * 4096 + (rr * 4 + w) * 512;
                GLDS16(gp, lp);
            }
        }
        __syncthreads();
        #pragma unroll
        for (int ks = 0; ks < 2; ++ks) {
            shortx8 ah[4], al[4], bh2[2], bl2[2];
            #pragma unroll
            for (int mi = 0; mi < 4; ++mi) {
                int row = wm + mi * 16 + l16;
                int s = (ks * 4 + quad) ^ (row & 7);      // swizzled read
                ah[mi] = *(const shortx8*)&sm[row * 64 + s * 8];
                al[mi] = *(const shortx8*)&sm[8192 + row * 64 + s * 8];
            }
            #pragma unroll
            for (int ni = 0; ni < 2; ++ni) {
                int row = wn + ni * 16 + l16;
                int s = (ks * 4 + quad) ^ (row & 7);
                bh2[ni] = *(const shortx8*)&sm[16384 + row * 64 + s * 8];
                bl2[ni] = *(const shortx8*)&sm[20480 + row * 64 + s * 8];
            }
            #pragma unroll
            for (int mi = 0; mi < 4; ++mi)
                #pragma unroll
                for (int ni = 0; ni < 2; ++ni) {
                    acc[mi][ni] = __builtin_amdgcn_mfma_f32_16x16x32_bf16(ah[mi], bh2[ni], acc[mi][ni], 0, 0, 0);
                    acc[mi][ni] = __builtin_amdgcn_mfma_f32_16x16x32_bf16(ah[mi], bl2[ni], acc[mi][ni], 0, 0, 0);
                    acc[mi][ni] = __builtin_amdgcn_mfma_f32_16x16x32_bf16(al[mi], bh2[ni], acc[mi][ni], 0, 0, 0);
                }
        }
    }
    #pragma unroll
    for (int ni = 0; ni < 2; ++ni) {
        int col = bn0 + wn + ni * 16 + l16;
        if (col < N) {
            float bv = (mode & EP_ACC) ? 0.f : bias[col];
            #pragma unroll
            for (int mi = 0; mi < 4; ++mi) {
                #pragma unroll
                for (int r = 0; r < 4; ++r) {
                    int row = bm0 + wm + mi * 16 + quad * 4 + r;
                    size_t o = (size_t)row * N + col;
                    float v = acc[mi][ni][r] + bv;
                    if ((mode & EP_RELU) && v < 0.f) v = 0.f;
                    if (mode & EP_ACC) v += Cf[o];
                    if (mode & EP_F32) Cf[o] = v;
                    if (mode & EP_PL) {
                        u16 hh, ll; bfsplit(v, hh, ll);
                        Ch[o] = hh; Cl[o] = ll;
                    }
                }
            }
        }
    }
}

// per-head transpose of pre-split V planes:
// vh/vl [4096][512] -> Vt[bh][64 d][512 s] hi/lo
__global__ __launch_bounds__(256) void vtsplit_pp(const u16* __restrict__ vh,
                                                  const u16* __restrict__ vl,
                                                  u16* __restrict__ dh, u16* __restrict__ dl) {
    __shared__ u16 Th[64][72], Tl[64][72];
    const int t = threadIdx.x;
    const int s0 = blockIdx.x * 64;
    const int bh = blockIdx.y;
    const int b = bh >> 3, h = bh & 7;
    #pragma unroll
    for (int j = 0; j < 2; ++j) {
        int idx = j * 256 + t;          // 0..511 segs of 8 u16
        int r = idx >> 3, sg = idx & 7;
        size_t src = (size_t)(b * SEQ + s0 + r) * DIM + h * 64 + sg * 8;
        *(uint4*)&Th[r][sg * 8] = *(const uint4*)(vh + src);
        *(uint4*)&Tl[r][sg * 8] = *(const uint4*)(vl + src);
    }
    __syncthreads();
    #pragma unroll
    for (int j = 0; j < 2; ++j) {
        int idx = j * 256 + t;
        int d = idx >> 3, sg = idx & 7;
        union { u16 e[8]; uint4 q; } xh, xl;
        #pragma unroll
        for (int k = 0; k < 8; ++k) { xh.e[k] = Th[sg * 8 + k][d]; xl.e[k] = Tl[sg * 8 + k][d]; }
        size_t dst = ((size_t)bh * 64 + d) * SEQ + s0 + sg * 8;
        *(uint4*)(dh + dst) = xh.q;
        *(uint4*)(dl + dst) = xl.q;
    }
}

// MFMA attention, plane-native I/O. One block = 64 query rows of one (b,h).
__global__ __launch_bounds__(256, 2) void attn_mf(
    const u16* __restrict__ Qh, const u16* __restrict__ Ql,
    const u16* __restrict__ Kh, const u16* __restrict__ Kl,
    const u16* __restrict__ Vth, const u16* __restrict__ Vtl,
    const float* __restrict__ gam, u16* __restrict__ AOh, u16* __restrict__ AOl,
    int m0) {
    __shared__ __align__(16) u16 KV[2][64][72];
    __shared__ __align__(16) u16 PB[4][2][16][72];
    const int t = threadIdx.x;
    const int lane = t & 63, w = t >> 6;
    const int l16 = lane & 15, quad = lane >> 4;
    const int chunk = 7 - (int)blockIdx.x;
    const int h = blockIdx.y, b = blockIdx.z;
    const int bS = b * SEQ;
    const int bh = b * NHEAD + h;
    const int nch = chunk + 1, nkt = nch * 4;
    const int qrow0 = chunk * 64 + w * 16;
    const int qrow = qrow0 + l16;
    const int kmax = qrow - m0;
    const int srow = t >> 2, sseg = t & 3;

    float g = gam[h];
    float gamma = -((g > 20.f) ? g : log1pf(__expf(g)));

    shortx8 qh[2], ql[2];
    {
        const u16* qph = Qh + (size_t)(bS + qrow) * DIM + h * 64;
        const u16* qpl = Ql + (size_t)(bS + qrow) * DIM + h * 64;
        #pragma unroll
        for (int ks = 0; ks < 2; ++ks) {
            qh[ks] = *(const shortx8*)(qph + ks * 32 + quad * 8);
            ql[ks] = *(const shortx8*)(qpl + ks * 32 + quad * 8);
        }
    }

    floatx4 s[32];
    #pragma unroll
    for (int i = 0; i < 32; ++i) s[i] = (floatx4){0.f, 0.f, 0.f, 0.f};

    // ---- Phase 1: scoresT = K . Q^T ----
    #pragma unroll
    for (int c = 0; c < 8; ++c) {
        if (c < nch) {
            __syncthreads();
            {
                size_t src = (size_t)(bS + c * 64 + srow) * DIM + h * 64 + sseg * 16;
                *(uint4*)&KV[0][srow][sseg * 16]     = *(const uint4*)(Kh + src);
                *(uint4*)&KV[0][srow][sseg * 16 + 8] = *(const uint4*)(Kh + src + 8);
                *(uint4*)&KV[1][srow][sseg * 16]     = *(const uint4*)(Kl + src);
                *(uint4*)&KV[1][srow][sseg * 16 + 8] = *(const uint4*)(Kl + src + 8);
            }
            __syncthreads();
            #pragma unroll
            for (int kt = 0; kt < 4; ++kt) {
                shortx8 kh0 = *(const shortx8*)&KV[0][kt * 16 + l16][quad * 8];
                shortx8 kh1 = *(const shortx8*)&KV[0][kt * 16 + l16][32 + quad * 8];
                shortx8 kl0 = *(const shortx8*)&KV[1][kt * 16 + l16][quad * 8];
                shortx8 kl1 = *(const shortx8*)&KV[1][kt * 16 + l16][32 + quad * 8];
                floatx4 a = s[c * 4 + kt];
                a = __builtin_amdgcn_mfma_f32_16x16x32_bf16(kh0, qh[0], a, 0, 0, 0);
                a = __builtin_amdgcn_mfma_f32_16x16x32_bf16(kh1, qh[1], a, 0, 0, 0);
                a = __builtin_amdgcn_mfma_f32_16x16x32_bf16(kh0, ql[0], a, 0, 0, 0);
                a = __builtin_amdgcn_mfma_f32_16x16x32_bf16(kh1, ql[1], a, 0, 0, 0);
                a = __builtin_amdgcn_mfma_f32_16x16x32_bf16(kl0, qh[0], a, 0, 0, 0);
                a = __builtin_amdgcn_mfma_f32_16x16x32_bf16(kl1, qh[1], a, 0, 0, 0);
                s[c * 4 + kt] = a;
            }
        }
    }

    // ---- Phase 2: softmax -> cumsum decay -> second softmax ----
    float m1 = -1e30f;
    #pragma unroll
    for (int kt = 0; kt < 32; ++kt) {
        if (kt < nkt) {
            #pragma unroll
            for (int r = 0; r < 4; ++r) {
                int key = kt * 16 + quad * 4 + r;
                float sv = (key <= kmax) ? s[kt][r] * 0.125f : -1e30f;
                s[kt][r] = sv;
                m1 = fmaxf(m1, sv);
            }
        }
    }
    m1 = fmaxf(m1, __shfl_xor(m1, 16, 64));
    m1 = fmaxf(m1, __shfl_xor(m1, 32, 64));

    float sum1 = 0.f;
    #pragma unroll
    for (int kt = 0; kt < 32; ++kt) {
        if (kt < nkt) {
            #pragma unroll
            for (int r = 0; r < 4; ++r) sum1 += __expf(s[kt][r] - m1);
        }
    }
    sum1 += __shfl_xor(sum1, 16, 64);
    sum1 += __shfl_xor(sum1, 32, 64);
    float inv1 = 1.f / sum1;

    float carry = 0.f, m2 = -1e30f;
    #pragma unroll
    for (int kt = 0; kt < 32; ++kt) {
        if (kt < nkt) {
            float e0 = __expf(s[kt][0] - m1);
            float e1 = __expf(s[kt][1] - m1);
            float e2 = __expf(s[kt][2] - m1);
            float e3 = __expf(s[kt][3] - m1);
            float c0 = e0, c1 = c0 + e1, c2 = c1 + e2, c3 = c2 + e3;
            float q0 = __shfl(c3, l16, 64);
            float q1 = __shfl(c3, l16 + 16, 64);
            float q2 = __shfl(c3, l16 + 32, 64);
            float q3 = __shfl(c3, l16 + 48, 64);
            float excl = carry;
            if (quad > 0) excl += q0;
            if (quad > 1) excl += q1;
            if (quad > 2) excl += q2;
            carry += q0 + q1 + q2 + q3;
            float cc[4] = {c0, c1, c2, c3};
            #pragma unroll
            for (int r = 0; r < 4; ++r) {
                int key = kt * 16 + quad * 4 + r;
                float distcum = (excl + cc[r]) * inv1;
                float rem = fmaxf(1.f - distcum, 0.f);
                float prod = fmaxf(rem * (float)(qrow - key), 0.f);
                float te = fmaxf(__expf(sqrtf(prod) * gamma), 1e-5f);
                te = fminf(te, 1e5f);
                float sv2 = s[kt][r] * te;
                s[kt][r] = sv2;
                m2 = fmaxf(m2, sv2);
            }
        }
    }
    m2 = fmaxf(m2, __shfl_xor(m2, 16, 64));
    m2 = fmaxf(m2, __shfl_xor(m2, 32, 64));

    float sum2 = 0.f;
    #pragma unroll
    for (int kt = 0; kt < 32; ++kt) {
        if (kt < nkt) {
            #pragma unroll
            for (int r = 0; r < 4; ++r) {
                float p = __expf(s[kt][r] - m2);
                s[kt][r] = p;
                sum2 += p;
            }
        }
    }
    sum2 += __shfl_xor(sum2, 16, 64);
    sum2 += __shfl_xor(sum2, 32, 64);
    float inv2 = 1.f / sum2;

    // ---- Phase 3: O = P . V ----
    floatx4 o[4];
    #pragma unroll
    for (int i = 0; i < 4; ++i) o[i] = (floatx4){0.f, 0.f, 0.f, 0.f};

    #pragma unroll
    for (int c = 0; c < 8; ++c) {
        if (c < nch) {
            __syncthreads();
            {
                size_t src = ((size_t)bh * 64 + srow) * SEQ + c * 64 + sseg * 16;
                *(uint4*)&KV[0][srow][sseg * 16]     = *(const uint4*)(Vth + src);
                *(uint4*)&KV[0][srow][sseg * 16 + 8] = *(const uint4*)(Vth + src + 8);
                *(uint4*)&KV[1][srow][sseg * 16]     = *(const uint4*)(Vtl + src);
                *(uint4*)&KV[1][srow][sseg * 16 + 8] = *(const uint4*)(Vtl + src + 8);
            }
            #pragma unroll
            for (int kt = 0; kt < 4; ++kt) {
                floatx4 pv = s[c * 4 + kt];
                u16 hh[4], ll[4];
                #pragma unroll
                for (int r = 0; r < 4; ++r) bfsplit(pv[r] * inv2, hh[r], ll[r]);
                uint2 hw, lw;
                hw.x = (unsigned)hh[0] | ((unsigned)hh[1] << 16);
                hw.y = (unsigned)hh[2] | ((unsigned)hh[3] << 16);
                lw.x = (unsigned)ll[0] | ((unsigned)ll[1] << 16);
                lw.y = (unsigned)ll[2] | ((unsigned)ll[3] << 16);
                *(uint2*)&PB[w][0][l16][kt * 16 + quad * 4] = hw;
                *(uint2*)&PB[w][1][l16][kt * 16 + quad * 4] = lw;
            }
            __syncthreads();
            shortx8 ph0 = *(const shortx8*)&PB[w][0][l16][quad * 8];
            shortx8 ph1 = *(const shortx8*)&PB[w][0][l16][32 + quad * 8];
            shortx8 pl0 = *(const shortx8*)&PB[w][1][l16][quad * 8];
            shortx8 pl1 = *(const shortx8*)&PB[w][1][l16][32 + quad * 8];
            #pragma unroll
            for (int dt = 0; dt < 4; ++dt) {
                shortx8 vh0 = *(const shortx8*)&KV[0][dt * 16 + l16][quad * 8];
                shortx8 vh1 = *(const shortx8*)&KV[0][dt * 16 + l16][32 + quad * 8];
                shortx8 vl0 = *(const shortx8*)&KV[1][dt * 16 + l16][quad * 8];
                shortx8 vl1 = *(const shortx8*)&KV[1][dt * 16 + l16][32 + quad * 8];
                floatx4 a = o[dt];
                a = __builtin_amdgcn_mfma_f32_16x16x32_bf16(ph0, vh0, a, 0, 0, 0);
                a = __builtin_amdgcn_mfma_f32_16x16x32_bf16(ph1, vh1, a, 0, 0, 0);
                a = __builtin_amdgcn_mfma_f32_16x16x32_bf16(ph0, vl0, a, 0, 0, 0);
                a = __builtin_amdgcn_mfma_f32_16x16x32_bf16(ph1, vl1, a, 0, 0, 0);
                a = __builtin_amdgcn_mfma_f32_16x16x32_bf16(pl0, vh0, a, 0, 0, 0);
                a = __builtin_amdgcn_mfma_f32_16x16x32_bf16(pl1, vh1, a, 0, 0, 0);
                o[dt] = a;
            }
        }
    }

    #pragma unroll
    for (int dt = 0; dt < 4; ++dt) {
        #pragma unroll
        for (int r = 0; r < 4; ++r) {
            int row = qrow0 + quad * 4 + r;
            float v = o[dt][r];
            if (m0 && row == 0) v = 0.f;
            u16 hh, ll; bfsplit(v, hh, ll);
            size_t oo = (size_t)(bS + row) * DIM + h * 64 + dt * 16 + l16;
            AOh[oo] = hh; AOl[oo] = ll;
        }
    }
}

static void run_wsplit(const float* W, u16* Bh, u16* Bl, int N, int K, int Npad,
                       hipStream_t stream) {
    wsplit<<<dim3(K / 64, Npad / 64), dim3(256), 0, stream>>>(W, Bh, Bl, N, K);
}
static void run_gemm(const u16* Ah, const u16* Al, const u16* Bh, const u16* Bl,
                     int K, int Bstride, int Boff, const float* bias, int N, int mode,
                     float* Cf, u16* Ch, u16* Cl, hipStream_t stream) {
    int Npad = (N + 63) & ~63;
    dim3 g(Npad / 64, TOK / 128);
    gemm_pp<<<g, dim3(256), 0, stream>>>(Ah, Al, Bh, Bl, K, Bstride, Boff,
                                         bias, N, mode, Cf, Ch, Cl);
}

extern "C" void kernel_launch(void* const* d_in, const int* in_sizes, int n_in,
                              void* d_out, int out_size, void* d_ws, size_t ws_size,
                              hipStream_t stream) {
    (void)in_sizes; (void)n_in;
    const int* c_data    = (const int*)d_in[0];
    const int* ca_data   = (const int*)d_in[1];
    const float* c_emb   = (const float*)d_in[2];
    const float* ca_emb  = (const float*)d_in[3];
    const float* Wk  = (const float*)d_in[4];
    const float* bk  = (const float*)d_in[5];
    const float* Wv  = (const float*)d_in[6];
    const float* bv  = (const float*)d_in[7];
    const float* Wo  = (const float*)d_in[8];
    const float* bo  = (const float*)d_in[9];
    const float* gammas = (const float*)d_in[10];
    const float* ln1s = (const float*)d_in[11];
    const float* ln1b = (const float*)d_in[12];
    const float* W1  = (const float*)d_in[13];
    const float* b1  = (const float*)d_in[14];
    const float* W2  = (const float*)d_in[15];
    const float* b2  = (const float*)d_in[16];
    const float* ln2s = (const float*)d_in[17];
    const float* ln2b = (const float*)d_in[18];
    const float* oW0 = (const float*)d_in[19];
    const float* ob0 = (const float*)d_in[20];
    const float* oW1 = (const float*)d_in[21];
    const float* ob1 = (const float*)d_in[22];
    const float* oW2 = (const float*)d_in[23];
    const float* ob2 = (const float*)d_in[24];

    float* out = (float*)d_out;
    const size_t MB = 1024 * 1024;
    if (ws_size < 64 * MB) {
        VAKT_52226802319686_kernel<<<dim3((out_size + 255) / 256), dim3(256), 0, stream>>>(out, out_size);
        return;
    }
    char* wsp = (char*)d_ws;
    // persistent
    float* x0b = (float*)(wsp);               // [0,8)
    float* yb  = (float*)(wsp + 8 * MB);      // [8,16)
    float* xb  = (float*)(wsp + 16 * MB);     // [16,24)
    u16* x0h = (u16*)(wsp + 24 * MB); u16* x0l = (u16*)(wsp + 28 * MB);
    u16* yph = (u16*)(wsp + 32 * MB); u16* ypl = (u16*)(wsp + 36 * MB);
    u16* xph = (u16*)(wsp + 40 * MB); u16* xpl = (u16*)(wsp + 44 * MB);
    // scratch (liveness-overlapped)
    u16* qph = (u16*)(wsp + 56 * MB); u16* qpl = (u16*)(wsp + 60 * MB);
    u16* btWk_h = (u16*)(wsp + 48 * MB);
    u16* btWk_l = (u16*)(wsp + 48 * MB + 512 * 1024);
    u16* btWv_h = (u16*)(wsp + 49 * MB);
    u16* btWv_l = (u16*)(wsp + 49 * MB + 512 * 1024);
    u16* Vth = (u16*)(wsp + 48 * MB); u16* Vtl = (u16*)(wsp + 52 * MB);
    u16* btWo_h = (u16*)(wsp + 56 * MB);
    u16* btWo_l = (u16*)(wsp + 56 * MB + 512 * 1024);
    float* t1 = (float*)(wsp + 48 * MB);      // [48,56), after attn
    u16* btW1_h = (u16*)(wsp + 56 * MB); u16* btW1_l = (u16*)(wsp + 58 * MB);
    u16* btW2_h = (u16*)(wsp + 60 * MB); u16* btW2_l = (u16*)(wsp + 62 * MB);
    // head
    u16* hcath = (u16*)(wsp + 24 * MB); u16* hcatl = (u16*)(wsp + 32 * MB);
    u16* btH_h = (u16*)(wsp + 48 * MB); u16* btH_l = (u16*)(wsp + 50 * MB);
    u16* h1h = (u16*)(wsp + 56 * MB); u16* h1l = (u16*)(wsp + 60 * MB);
    u16* h2h = (u16*)(wsp);           u16* h2l = (u16*)(wsp + 8 * MB);

    embed_pp<<<dim3(TOK), dim3(256), 0, stream>>>(c_data, ca_data, c_emb, ca_emb,
                                                  x0b, yb, x0h, x0l, yph, ypl);

    for (int li = 0; li < 6; ++li) {
        const u16 *qsh, *qsl, *ksh, *ksl, *vsh, *vsl;
        const float* resid; float* outb; u16 *outph, *outpl;
        u16 *kph, *kpl, *vph, *vpl, *ffh, *ffl;
        int m0, pos;
        if (li == 0 || li == 1) {
            qsh = yph; qsl = ypl; ksh = x0h; ksl = x0l; vsh = yph; vsl = ypl;
            resid = yb; outb = yb; outph = yph; outpl = ypl; m0 = 0; pos = 1;
            kph = (u16*)(wsp + 16 * MB); kpl = (u16*)(wsp + 20 * MB);   // xb slot
            vph = (u16*)(wsp + 40 * MB); vpl = (u16*)(wsp + 44 * MB);   // xp slot
            ffh = (u16*)(wsp + 16 * MB); ffl = (u16*)(wsp + 40 * MB);
        } else if (li == 2) {
            qsh = x0h; qsl = x0l; ksh = x0h; ksl = x0l; vsh = x0h; vsl = x0l;
            resid = x0b; outb = xb; outph = xph; outpl = xpl; m0 = 0; pos = 0;
            kph = qph; kpl = qpl;
            vph = (u16*)(wsp + 16 * MB); vpl = (u16*)(wsp + 20 * MB);   // xb slot
            ffh = nullptr; ffl = nullptr;
        } else {
            int odd = (li == 3 || li == 5);
            qsh = xph; qsl = xpl; ksh = xph; ksl = xpl;
            if (odd) { vsh = yph; vsl = ypl; } else { vsh = xph; vsl = xpl; }
            resid = xb; outb = xb; outph = xph; outpl = xpl;
            m0 = odd ? 1 : 0; pos = odd ? 1 : 0;
            kph = qph; kpl = qpl;
            vph = (u16*)(wsp + 24 * MB); vpl = (u16*)(wsp + 28 * MB);   // x0p slot
            ffh = (u16*)(wsp + 8 * MB);  ffl = (u16*)(wsp + 24 * MB);   // yb + x0p slots
        }
        u16* aoph = vph; u16* aopl = vpl;   // vp dead after vtsplit

        run_wsplit(Wk + (size_t)li * DIM * DIM, btWk_h, btWk_l, DIM, DIM, DIM, stream);
        run_wsplit(Wv + (size_t)li * DIM * DIM, btWv_h, btWv_l, DIM, DIM, DIM, stream);
        run_gemm(qsh, qsl, btWk_h, btWk_l, DIM, DIM, 0, bk + li * DIM, DIM, EP_PL,
                 nullptr, qph, qpl, stream);
        if (ksh != qsh) {
            run_gemm(ksh, ksl, btWk_h, btWk_l, DIM, DIM, 0, bk + li * DIM, DIM, EP_PL,
                     nullptr, kph, kpl, stream);
        }
        run_gemm(vsh, vsl, btWv_h, btWv_l, DIM, DIM, 0, bv + li * DIM, DIM, EP_PL,
                 nullptr, vph, vpl, stream);
        vtsplit_pp<<<dim3(SEQ / 64, BATCH * NHEAD), dim3(256), 0, stream>>>(vph, vpl, Vth, Vtl);
        attn_mf<<<dim3(8, NHEAD, BATCH), dim3(256), 0, stream>>>(
            qph, qpl, kph, kpl, Vth, Vtl, gammas + li * NHEAD, aoph, aopl, m0);
        run_wsplit(Wo + (size_t)li * DIM * DIM, btWo_h, btWo_l, DIM, DIM, DIM, stream);
        run_gemm(aoph, aopl, btWo_h, btWo_l, DIM, DIM, 0, bo + li * DIM, DIM, EP_F32,
                 t1, nullptr, nullptr, stream);
        add_ln_pp<<<dim3(TOK / 4), dim3(256), 0, stream>>>(resid, t1, ln1s + li * DIM,
                                                           ln1b + li * DIM, outb, outph, outpl);
        if (pos) {
            run_wsplit(W1 + (size_t)li * DIM * FFD, btW1_h, btW1_l, FFD, DIM, FFD, stream);
            run_wsplit(W2 + (size_t)li * FFD * DIM, btW2_h, btW2_l, DIM, FFD, DIM, stream);
            for (int c = 0; c < 2; ++c) {
                run_gemm(outph, outpl,
                         btW1_h + (size_t)c * 1024 * DIM, btW1_l + (size_t)c * 1024 * DIM,
                         DIM, DIM, 0, b1 + li * FFD + c * 1024, 1024, EP_RELU | EP_PL,
                         nullptr, ffh, ffl, stream);
                run_gemm(ffh, ffl, btW2_h, btW2_l, 1024, FFD, c * 1024,
                         b2 + li * DIM, DIM, (c == 0) ? EP_F32 : (EP_F32 | EP_ACC),
                         t1, nullptr, nullptr, stream);
            }
            add_ln_pp<<<dim3(TOK / 4), dim3(256), 0, stream>>>(outb, t1, ln2s + li * DIM,
                                                               ln2b + li * DIM, outb, outph, outpl);
        }
    }

    concat_pp<<<dim3(TOK), dim3(256), 0, stream>>>(xb, x0b, hcath, hcatl);
    run_wsplit(oW0, btH_h, btH_l, 512, 1024, 512, stream);
    run_gemm(hcath, hcatl, btH_h, btH_l, 1024, 1024, 0, ob0, 512, EP_RELU | EP_PL,
             nullptr, h1h, h1l, stream);
    run_wsplit(oW1, btH_h, btH_l, 1024, 512, 1024, stream);
    run_gemm(h1h, h1l, btH_h, btH_l, 512, 512, 0, ob1, 1024, EP_RELU | EP_PL,
             nullptr, h2h, h2l, stream);
    run_wsplit(oW2, btH_h, btH_l, 1000, 1024, 1024, stream);
    run_gemm(h2h, h2l, btH_h, btH_l, 1024, 1024, 0, ob2, 1000, EP_F32,
             out, nullptr, nullptr, stream);
}

// Round 3
// 1705.827 us; speedup vs baseline: 1.8832x; 1.0322x over previous
//
#include <hip/hip_runtime.h>

#define TOK 4096
#define SEQ 512
#define BATCH 8
#define DIM 512
#define NHEAD 8
#define DK 64
#define FFD 2048

typedef unsigned short u16;
typedef unsigned int u32;
typedef float floatx4 __attribute__((ext_vector_type(4)));
typedef short shortx8 __attribute__((ext_vector_type(8)));

// epilogue mode bits
#define EP_RELU 1
#define EP_ACC  2
#define EP_F32  4
#define EP_PL   8

__device__ __forceinline__ u16 bfh(float f) {
    union { float f; unsigned u; } x; x.f = f;
    return (u16)((x.u + 0x7fffu + ((x.u >> 16) & 1u)) >> 16);
}
__device__ __forceinline__ float bff(u16 h) {
    union { unsigned u; float f; } x; x.u = (unsigned)h << 16; return x.f;
}
// truncation-based hi/lo split: residual ~2^-16 relative
__device__ __forceinline__ void bfsplit(float v, u16& h, u16& l) {
    union { float f; unsigned u; } x; x.f = v;
    union { unsigned u; float f; } hb; hb.u = x.u & 0xffff0000u;
    float rem = v - hb.f;
    union { float f; unsigned u; } rr; rr.f = rem;
    h = (u16)(x.u >> 16);
    l = (u16)(rr.u >> 16);
}
__device__ __forceinline__ float wave_sum(float v) {
    #pragma unroll
    for (int off = 32; off; off >>= 1) v += __shfl_xor(v, off, 64);
    return v;
}

#define GLDS16(gp, lp) __builtin_amdgcn_global_load_lds( \
    (const __attribute__((address_space(1))) u32*)(const void*)(gp), \
    (__attribute__((address_space(3))) u32*)(void*)(lp), 16, 0, 0)

// sentinel: ws too small
__global__ void VAKT_52226802319686_kernel(float* out, int n) {
    int i = blockIdx.x * 256 + threadIdx.x;
    if (i < n) out[i] = 524288.f;
}

__global__ void embed_pp(const int* cd, const int* cad, const float* cemb,
                         const float* caemb, float* x0, float* y,
                         u16* x0h, u16* x0l, u16* yh, u16* yl) {
    int tok = blockIdx.x;
    int idx = cd[tok];
    int resp = (cad[tok] - idx) / 1000;
    for (int d = threadIdx.x; d < DIM; d += 256) {
        float e = cemb[(size_t)idx * DIM + d];
        float yv = e + caemb[resp * DIM + d];
        size_t o = (size_t)tok * DIM + d;
        x0[o] = e; y[o] = yv;
        u16 hh, ll;
        bfsplit(e, hh, ll);  x0h[o] = hh; x0l[o] = ll;
        bfsplit(yv, hh, ll); yh[o] = hh;  yl[o] = ll;
    }
}

__global__ void concat_pp(const float* X, const float* X0, u16* Hh, u16* Hl) {
    int tok = blockIdx.x;
    for (int d = threadIdx.x; d < 2 * DIM; d += 256) {
        float v = (d < DIM) ? X[(size_t)tok * DIM + d] : X0[(size_t)tok * DIM + d - DIM];
        u16 hh, ll; bfsplit(v, hh, ll);
        Hh[(size_t)tok * (2 * DIM) + d] = hh;
        Hl[(size_t)tok * (2 * DIM) + d] = ll;
    }
}

__global__ void add_ln_pp(const float* X, const float* Dl, const float* sc,
                          const float* bi, float* O, u16* Oh, u16* Ol) {
    int lane = threadIdx.x & 63, w = threadIdx.x >> 6;
    size_t row = (size_t)blockIdx.x * 4 + w;
    const float* xr = X + row * DIM;
    const float* dr = Dl + row * DIM;
    float v[8]; float sum = 0.f, sq = 0.f;
    for (int i = 0; i < 8; i++) {
        int d = i * 64 + lane;
        float t = xr[d] + dr[d];
        v[i] = t; sum += t; sq += t * t;
    }
    sum = wave_sum(sum); sq = wave_sum(sq);
    float mean = sum * (1.0f / 512.0f);
    float var = sq * (1.0f / 512.0f) - mean * mean;
    float rstd = rsqrtf(var + 1e-5f);
    float* orow = O + row * DIM;
    for (int i = 0; i < 8; i++) {
        int d = i * 64 + lane;
        float val = (v[i] - mean) * rstd * sc[d] + bi[d];
        orow[d] = val;
        u16 hh, ll; bfsplit(val, hh, ll);
        Oh[row * DIM + d] = hh; Ol[row * DIM + d] = ll;
    }
}

// weights W[K][N] fp32 -> Bt hi/lo u16 [Npad][K] (transposed + bf16-split)
__global__ __launch_bounds__(256) void wsplit(const float* W, u16* Bh, u16* Bl,
                                              int N, int K) {
    __shared__ float T[64][65];
    int t = threadIdx.x;
    int k0 = blockIdx.x * 64, n0 = blockIdx.y * 64;
    for (int i = 0; i < 16; i++) {
        int idx = i * 256 + t;
        int kr = idx >> 6, nc = idx & 63;
        int gn = n0 + nc;
        T[kr][nc] = (gn < N) ? W[(size_t)(k0 + kr) * N + gn] : 0.f;
    }
    __syncthreads();
    for (int i = 0; i < 16; i++) {
        int idx = i * 256 + t;
        int nr = idx >> 6, kc = idx & 63;
        float v = T[kc][nr];
        u16 h = bfh(v);
        float rem = v - bff(h);
        size_t o = (size_t)(n0 + nr) * K + k0 + kc;
        Bh[o] = h; Bl[o] = bfh(rem);
    }
}

// fused double-wsplit for two 512x512 weights (Wk, Wv) -> one launch
__global__ __launch_bounds__(256) void wsplit2(const float* Wa, const float* Wb,
                                               u16* Ah_, u16* Al_,
                                               u16* Bh_, u16* Bl_) {
    __shared__ float T[64][65];
    const float* W = blockIdx.z ? Wb : Wa;
    u16* Bh = blockIdx.z ? Bh_ : Ah_;
    u16* Bl = blockIdx.z ? Bl_ : Al_;
    int t = threadIdx.x;
    int k0 = blockIdx.x * 64, n0 = blockIdx.y * 64;
    for (int i = 0; i < 16; i++) {
        int idx = i * 256 + t;
        int kr = idx >> 6, nc = idx & 63;
        T[kr][nc] = W[(size_t)(k0 + kr) * DIM + n0 + nc];
    }
    __syncthreads();
    for (int i = 0; i < 16; i++) {
        int idx = i * 256 + t;
        int nr = idx >> 6, kc = idx & 63;
        float v = T[kc][nr];
        u16 h = bfh(v);
        float rem = v - bff(h);
        size_t o = (size_t)(n0 + nr) * DIM + k0 + kc;
        Bh[o] = h; Bl[o] = bfh(rem);
    }
}

// C[4096,N] = A @ Bt^T (+bias). A as pre-split u16 planes [4096][K] (hi,lo).
// B pre-split [Npad][Bstride] with k-window at Boff. 128x64 tile, BK=64,
// 4 waves x (64x32). global_load_lds staging with source-side XOR swizzle.
__global__ __launch_bounds__(256) void gemm_pp(
    const u16* __restrict__ Ah, const u16* __restrict__ Al,
    const u16* __restrict__ Bh, const u16* __restrict__ Bl,
    int K, int Bstride, int Boff,
    const float* __restrict__ bias, int N, int mode,
    float* __restrict__ Cf, u16* __restrict__ Ch, u16* __restrict__ Cl) {
    // layout: Ah tile [128][64] @0, Al @8192, Bh [64][64] @16384, Bl @20480 (u16 units)
    __shared__ u16 sm[24576];
    const int t = threadIdx.x;
    const int lane = t & 63, w = t >> 6;
    const int l16 = lane & 15, quad = lane >> 4;
    const int bm0 = blockIdx.y * 128, bn0 = blockIdx.x * 64;
    const int wm = (w & 1) * 64, wn = (w >> 1) * 32;

    floatx4 acc[4][2];
    #pragma unroll
    for (int mi = 0; mi < 4; mi++)
        #pragma unroll
        for (int ni = 0; ni < 2; ni++) acc[mi][ni] = (floatx4){0.f, 0.f, 0.f, 0.f};

    for (int k0 = 0; k0 < K; k0 += 64) {
        __syncthreads();
        // stage A: 2 planes x 4 rounds (wave covers 64 x 16B per round)
        #pragma unroll
        for (int p = 0; p < 2; ++p) {
            const u16* Asrc = p ? Al : Ah;
            #pragma unroll
            for (int rr = 0; rr < 4; ++rr) {
                int idx = (rr * 4 + w) * 64 + lane;       // 16B-seg index, 0..1023
                int row = idx >> 3;
                int sg = (idx & 7) ^ (row & 7);           // source-side swizzle
                const u16* gp = Asrc + (size_t)(bm0 + row) * K + k0 + sg * 8;
                u16* lp = sm + p * 8192 + (rr * 4 + w) * 512;  // wave-uniform
                GLDS16(gp, lp);
            }
        }
        // stage B: 2 planes x 2 rounds
        #pragma unroll
        for (int p = 0; p < 2; ++p) {
            const u16* Bsrc = p ? Bl : Bh;
            #pragma unroll
            for (int rr = 0; rr < 2; ++rr) {
                int idx = (rr * 4 + w) * 64 + lane;       // 0..511
                int row = idx >> 3;
                int sg = (idx & 7) ^ (row & 7);
                const u16* gp = Bsrc + (size_t)(bn0 + row) * Bstride + Boff + k0 + sg * 8;
                u16* lp = sm + 16384 + p * 4096 + (rr * 4 + w) * 512;
                GLDS16(gp, lp);
            }
        }
        __syncthreads();
        #pragma unroll
        for (int ks = 0; ks < 2; ++ks) {
            shortx8 ah[4], al[4], bh2[2], bl2[2];
            #pragma unroll
            for (int mi = 0; mi < 4; ++mi) {
                int row = wm + mi * 16 + l16;
                int s = (ks * 4 + quad) ^ (row & 7);      // swizzled read
                ah[mi] = *(const shortx8*)&sm[row * 64 + s * 8];
                al[mi] = *(const shortx8*)&sm[8192 + row * 64 + s * 8];
            }
            #pragma unroll
            for (int ni = 0; ni < 2; ++ni) {
                int row = wn + ni * 16 + l16;
                int s = (ks * 4 + quad) ^ (row & 7);
                bh2[ni] = *(const shortx8*)&sm[16384 + row * 64 + s * 8];
                bl2[ni] = *(const shortx8*)&sm[20480 + row * 64 + s * 8];
            }
            #pragma unroll
            for (int mi = 0; mi < 4; ++mi)
                #pragma unroll
                for (int ni = 0; ni < 2; ++ni) {
                    acc[mi][ni] = __builtin_amdgcn_mfma_f32_16x16x32_bf16(ah[mi], bh2[ni], acc[mi][ni], 0, 0, 0);
                    acc[mi][ni] = __builtin_amdgcn_mfma_f32_16x16x32_bf16(ah[mi], bl2[ni], acc[mi][ni], 0, 0, 0);
                    acc[mi][ni] = __builtin_amdgcn_mfma_f32_16x16x32_bf16(al[mi], bh2[ni], acc[mi][ni], 0, 0, 0);
                }
        }
    }
    #pragma unroll
    for (int ni = 0; ni < 2; ++ni) {
        int col = bn0 + wn + ni * 16 + l16;
        if (col < N) {
            float bv = (mode & EP_ACC) ? 0.f : bias[col];
            #pragma unroll
            for (int mi = 0; mi < 4; ++mi) {
                #pragma unroll
                for (int r = 0; r < 4; ++r) {
                    int row = bm0 + wm + mi * 16 + quad * 4 + r;
                    size_t o = (size_t)row * N + col;
                    float v = acc[mi][ni][r] + bv;
                    if ((mode & EP_RELU) && v < 0.f) v = 0.f;
                    if (mode & EP_ACC) v += Cf[o];
                    if (mode & EP_F32) Cf[o] = v;
                    if (mode & EP_PL) {
                        u16 hh, ll; bfsplit(v, hh, ll);
                        Ch[o] = hh; Cl[o] = ll;
                    }
                }
            }
        }
    }
}

// per-head transpose of pre-split V planes:
// vh/vl [4096][512] -> Vt[bh][64 d][512 s] hi/lo
__global__ __launch_bounds__(256) void vtsplit_pp(const u16* __restrict__ vh,
                                                  const u16* __restrict__ vl,
                                                  u16* __restrict__ dh, u16* __restrict__ dl) {
    __shared__ u16 Th[64][72], Tl[64][72];
    const int t = threadIdx.x;
    const int s0 = blockIdx.x * 64;
    const int bh = blockIdx.y;
    const int b = bh >> 3, h = bh & 7;
    #pragma unroll
    for (int j = 0; j < 2; ++j) {
        int idx = j * 256 + t;          // 0..511 segs of 8 u16
        int r = idx >> 3, sg = idx & 7;
        size_t src = (size_t)(b * SEQ + s0 + r) * DIM + h * 64 + sg * 8;
        *(uint4*)&Th[r][sg * 8] = *(const uint4*)(vh + src);
        *(uint4*)&Tl[r][sg * 8] = *(const uint4*)(vl + src);
    }
    __syncthreads();
    #pragma unroll
    for (int j = 0; j < 2; ++j) {
        int idx = j * 256 + t;
        int d = idx >> 3, sg = idx & 7;
        union { u16 e[8]; uint4 q; } xh, xl;
        #pragma unroll
        for (int k = 0; k < 8; ++k) { xh.e[k] = Th[sg * 8 + k][d]; xl.e[k] = Tl[sg * 8 + k][d]; }
        size_t dst = ((size_t)bh * 64 + d) * SEQ + s0 + sg * 8;
        *(uint4*)(dh + dst) = xh.q;
        *(uint4*)(dl + dst) = xl.q;
    }
}

// MFMA attention, plane-native I/O. One block = 32 query rows of one (b,h):
// 2 waves x 16 rows, grid (16, 8, 8) = 1024 blocks -> all blocks co-resident
// (4/CU, 27.6 KB LDS) so the causal-length imbalance has no tail.
__global__ __launch_bounds__(128, 2) void attn_mf(
    const u16* __restrict__ Qh, const u16* __restrict__ Ql,
    const u16* __restrict__ Kh, const u16* __restrict__ Kl,
    const u16* __restrict__ Vth, const u16* __restrict__ Vtl,
    const float* __restrict__ gam, u16* __restrict__ AOh, u16* __restrict__ AOl,
    int m0) {
    __shared__ __align__(16) u16 KV[2][64][72];
    __shared__ __align__(16) u16 PB[2][2][16][72];
    const int t = threadIdx.x;
    const int lane = t & 63, w = t >> 6;          // w in {0,1}
    const int l16 = lane & 15, quad = lane >> 4;
    const int qt = 15 - (int)blockIdx.x;          // heavy q-tiles dispatch first
    const int h = blockIdx.y, b = blockIdx.z;
    const int bS = b * SEQ;
    const int bh = b * NHEAD + h;
    // chunks needed; identical for both waves (16-row halves of a 32-row tile
    // never straddle a 64-boundary differently), so barriers stay uniform.
    const int nch = ((qt * 32 + 31) >> 6) + 1;
    const int nkt = nch * 4;
    const int qrow0 = qt * 32 + w * 16;
    const int qrow = qrow0 + l16;
    const int kmax = qrow - m0;
    const int srow = t >> 1, sseg0 = (t & 1) * 4; // staging: 4x16B segs/thread/plane

    float g = gam[h];
    float gamma = -((g > 20.f) ? g : log1pf(__expf(g)));

    shortx8 qh[2], ql[2];
    {
        const u16* qph = Qh + (size_t)(bS + qrow) * DIM + h * 64;
        const u16* qpl = Ql + (size_t)(bS + qrow) * DIM + h * 64;
        #pragma unroll
        for (int ks = 0; ks < 2; ++ks) {
            qh[ks] = *(const shortx8*)(qph + ks * 32 + quad * 8);
            ql[ks] = *(const shortx8*)(qpl + ks * 32 + quad * 8);
        }
    }

    floatx4 s[32];
    #pragma unroll
    for (int i = 0; i < 32; ++i) s[i] = (floatx4){0.f, 0.f, 0.f, 0.f};

    // ---- Phase 1: scoresT = K . Q^T ----
    #pragma unroll
    for (int c = 0; c < 8; ++c) {
        if (c < nch) {
            __syncthreads();
            {
                size_t src = (size_t)(bS + c * 64 + srow) * DIM + h * 64 + sseg0 * 8;
                #pragma unroll
                for (int j = 0; j < 4; ++j) {
                    *(uint4*)&KV[0][srow][(sseg0 + j) * 8] = *(const uint4*)(Kh + src + j * 8);
                    *(uint4*)&KV[1][srow][(sseg0 + j) * 8] = *(const uint4*)(Kl + src + j * 8);
                }
            }
            __syncthreads();
            #pragma unroll
            for (int kt = 0; kt < 4; ++kt) {
                shortx8 kh0 = *(const shortx8*)&KV[0][kt * 16 + l16][quad * 8];
                shortx8 kh1 = *(const shortx8*)&KV[0][kt * 16 + l16][32 + quad * 8];
                shortx8 kl0 = *(const shortx8*)&KV[1][kt * 16 + l16][quad * 8];
                shortx8 kl1 = *(const shortx8*)&KV[1][kt * 16 + l16][32 + quad * 8];
                floatx4 a = s[c * 4 + kt];
                a = __builtin_amdgcn_mfma_f32_16x16x32_bf16(kh0, qh[0], a, 0, 0, 0);
                a = __builtin_amdgcn_mfma_f32_16x16x32_bf16(kh1, qh[1], a, 0, 0, 0);
                a = __builtin_amdgcn_mfma_f32_16x16x32_bf16(kh0, ql[0], a, 0, 0, 0);
                a = __builtin_amdgcn_mfma_f32_16x16x32_bf16(kh1, ql[1], a, 0, 0, 0);
                a = __builtin_amdgcn_mfma_f32_16x16x32_bf16(kl0, qh[0], a, 0, 0, 0);
                a = __builtin_amdgcn_mfma_f32_16x16x32_bf16(kl1, qh[1], a, 0, 0, 0);
                s[c * 4 + kt] = a;
            }
        }
    }

    // ---- Phase 2: softmax -> cumsum decay -> second softmax ----
    float m1 = -1e30f;
    #pragma unroll
    for (int kt = 0; kt < 32; ++kt) {
        if (kt < nkt) {
            #pragma unroll
            for (int r = 0; r < 4; ++r) {
                int key = kt * 16 + quad * 4 + r;
                float sv = (key <= kmax) ? s[kt][r] * 0.125f : -1e30f;
                s[kt][r] = sv;
                m1 = fmaxf(m1, sv);
            }
        }
    }
    m1 = fmaxf(m1, __shfl_xor(m1, 16, 64));
    m1 = fmaxf(m1, __shfl_xor(m1, 32, 64));

    float sum1 = 0.f;
    #pragma unroll
    for (int kt = 0; kt < 32; ++kt) {
        if (kt < nkt) {
            #pragma unroll
            for (int r = 0; r < 4; ++r) sum1 += __expf(s[kt][r] - m1);
        }
    }
    sum1 += __shfl_xor(sum1, 16, 64);
    sum1 += __shfl_xor(sum1, 32, 64);
    float inv1 = 1.f / sum1;

    float carry = 0.f, m2 = -1e30f;
    #pragma unroll
    for (int kt = 0; kt < 32; ++kt) {
        if (kt < nkt) {
            float e0 = __expf(s[kt][0] - m1);
            float e1 = __expf(s[kt][1] - m1);
            float e2 = __expf(s[kt][2] - m1);
            float e3 = __expf(s[kt][3] - m1);
            float c0 = e0, c1 = c0 + e1, c2 = c1 + e2, c3 = c2 + e3;
            float q0 = __shfl(c3, l16, 64);
            float q1 = __shfl(c3, l16 + 16, 64);
            float q2 = __shfl(c3, l16 + 32, 64);
            float q3 = __shfl(c3, l16 + 48, 64);
            float excl = carry;
            if (quad > 0) excl += q0;
            if (quad > 1) excl += q1;
            if (quad > 2) excl += q2;
            carry += q0 + q1 + q2 + q3;
            float cc[4] = {c0, c1, c2, c3};
            #pragma unroll
            for (int r = 0; r < 4; ++r) {
                int key = kt * 16 + quad * 4 + r;
                float distcum = (excl + cc[r]) * inv1;
                float rem = fmaxf(1.f - distcum, 0.f);
                float prod = fmaxf(rem * (float)(qrow - key), 0.f);
                float te = fmaxf(__expf(sqrtf(prod) * gamma), 1e-5f);
                te = fminf(te, 1e5f);
                float sv2 = s[kt][r] * te;
                s[kt][r] = sv2;
                m2 = fmaxf(m2, sv2);
            }
        }
    }
    m2 = fmaxf(m2, __shfl_xor(m2, 16, 64));
    m2 = fmaxf(m2, __shfl_xor(m2, 32, 64));

    float sum2 = 0.f;
    #pragma unroll
    for (int kt = 0; kt < 32; ++kt) {
        if (kt < nkt) {
            #pragma unroll
            for (int r = 0; r < 4; ++r) {
                float p = __expf(s[kt][r] - m2);
                s[kt][r] = p;
                sum2 += p;
            }
        }
    }
    sum2 += __shfl_xor(sum2, 16, 64);
    sum2 += __shfl_xor(sum2, 32, 64);
    float inv2 = 1.f / sum2;

    // ---- Phase 3: O = P . V ----
    floatx4 o[4];
    #pragma unroll
    for (int i = 0; i < 4; ++i) o[i] = (floatx4){0.f, 0.f, 0.f, 0.f};

    #pragma unroll
    for (int c = 0; c < 8; ++c) {
        if (c < nch) {
            __syncthreads();
            {
                size_t src = ((size_t)bh * 64 + srow) * SEQ + c * 64 + sseg0 * 8;
                #pragma unroll
                for (int j = 0; j < 4; ++j) {
                    *(uint4*)&KV[0][srow][(sseg0 + j) * 8] = *(const uint4*)(Vth + src + j * 8);
                    *(uint4*)&KV[1][srow][(sseg0 + j) * 8] = *(const uint4*)(Vtl + src + j * 8);
                }
            }
            #pragma unroll
            for (int kt = 0; kt < 4; ++kt) {
                floatx4 pv = s[c * 4 + kt];
                u16 hh[4], ll[4];
                #pragma unroll
                for (int r = 0; r < 4; ++r) bfsplit(pv[r] * inv2, hh[r], ll[r]);
                uint2 hw, lw;
                hw.x = (unsigned)hh[0] | ((unsigned)hh[1] << 16);
                hw.y = (unsigned)hh[2] | ((unsigned)hh[3] << 16);
                lw.x = (unsigned)ll[0] | ((unsigned)ll[1] << 16);
                lw.y = (unsigned)ll[2] | ((unsigned)ll[3] << 16);
                *(uint2*)&PB[w][0][l16][kt * 16 + quad * 4] = hw;
                *(uint2*)&PB[w][1][l16][kt * 16 + quad * 4] = lw;
            }
            __syncthreads();
            shortx8 ph0 = *(const shortx8*)&PB[w][0][l16][quad * 8];
            shortx8 ph1 = *(const shortx8*)&PB[w][0][l16][32 + quad * 8];
            shortx8 pl0 = *(const shortx8*)&PB[w][1][l16][quad * 8];
            shortx8 pl1 = *(const shortx8*)&PB[w][1][l16][32 + quad * 8];
            #pragma unroll
            for (int dt = 0; dt < 4; ++dt) {
                shortx8 vh0 = *(const shortx8*)&KV[0][dt * 16 + l16][quad * 8];
                shortx8 vh1 = *(const shortx8*)&KV[0][dt * 16 + l16][32 + quad * 8];
                shortx8 vl0 = *(const shortx8*)&KV[1][dt * 16 + l16][quad * 8];
                shortx8 vl1 = *(const shortx8*)&KV[1][dt * 16 + l16][32 + quad * 8];
                floatx4 a = o[dt];
                a = __builtin_amdgcn_mfma_f32_16x16x32_bf16(ph0, vh0, a, 0, 0, 0);
                a = __builtin_amdgcn_mfma_f32_16x16x32_bf16(ph1, vh1, a, 0, 0, 0);
                a = __builtin_amdgcn_mfma_f32_16x16x32_bf16(ph0, vl0, a, 0, 0, 0);
                a = __builtin_amdgcn_mfma_f32_16x16x32_bf16(ph1, vl1, a, 0, 0, 0);
                a = __builtin_amdgcn_mfma_f32_16x16x32_bf16(pl0, vh0, a, 0, 0, 0);
                a = __builtin_amdgcn_mfma_f32_16x16x32_bf16(pl1, vh1, a, 0, 0, 0);
                o[dt] = a;
            }
        }
    }

    #pragma unroll
    for (int dt = 0; dt < 4; ++dt) {
        #pragma unroll
        for (int r = 0; r < 4; ++r) {
            int row = qrow0 + quad * 4 + r;
            float v = o[dt][r];
            if (m0 && row == 0) v = 0.f;
            u16 hh, ll; bfsplit(v, hh, ll);
            size_t oo = (size_t)(bS + row) * DIM + h * 64 + dt * 16 + l16;
            AOh[oo] = hh; AOl[oo] = ll;
        }
    }
}

static void run_wsplit(const float* W, u16* Bh, u16* Bl, int N, int K, int Npad,
                       hipStream_t stream) {
    wsplit<<<dim3(K / 64, Npad / 64), dim3(256), 0, stream>>>(W, Bh, Bl, N, K);
}
static void run_gemm(const u16* Ah, const u16* Al, const u16* Bh, const u16* Bl,
                     int K, int Bstride, int Boff, const float* bias, int N, int mode,
                     float* Cf, u16* Ch, u16* Cl, hipStream_t stream) {
    int Npad = (N + 63) & ~63;
    dim3 g(Npad / 64, TOK / 128);
    gemm_pp<<<g, dim3(256), 0, stream>>>(Ah, Al, Bh, Bl, K, Bstride, Boff,
                                         bias, N, mode, Cf, Ch, Cl);
}

extern "C" void kernel_launch(void* const* d_in, const int* in_sizes, int n_in,
                              void* d_out, int out_size, void* d_ws, size_t ws_size,
                              hipStream_t stream) {
    (void)in_sizes; (void)n_in;
    const int* c_data    = (const int*)d_in[0];
    const int* ca_data   = (const int*)d_in[1];
    const float* c_emb   = (const float*)d_in[2];
    const float* ca_emb  = (const float*)d_in[3];
    const float* Wk  = (const float*)d_in[4];
    const float* bk  = (const float*)d_in[5];
    const float* Wv  = (const float*)d_in[6];
    const float* bv  = (const float*)d_in[7];
    const float* Wo  = (const float*)d_in[8];
    const float* bo  = (const float*)d_in[9];
    const float* gammas = (const float*)d_in[10];
    const float* ln1s = (const float*)d_in[11];
    const float* ln1b = (const float*)d_in[12];
    const float* W1  = (const float*)d_in[13];
    const float* b1  = (const float*)d_in[14];
    const float* W2  = (const float*)d_in[15];
    const float* b2  = (const float*)d_in[16];
    const float* ln2s = (const float*)d_in[17];
    const float* ln2b = (const float*)d_in[18];
    const float* oW0 = (const float*)d_in[19];
    const float* ob0 = (const float*)d_in[20];
    const float* oW1 = (const float*)d_in[21];
    const float* ob1 = (const float*)d_in[22];
    const float* oW2 = (const float*)d_in[23];
    const float* ob2 = (const float*)d_in[24];

    float* out = (float*)d_out;
    const size_t MB = 1024 * 1024;
    if (ws_size < 64 * MB) {
        VAKT_52226802319686_kernel<<<dim3((out_size + 255) / 256), dim3(256), 0, stream>>>(out, out_size);
        return;
    }
    char* wsp = (char*)d_ws;
    // persistent
    float* x0b = (float*)(wsp);               // [0,8)
    float* yb  = (float*)(wsp + 8 * MB);      // [8,16)
    float* xb  = (float*)(wsp + 16 * MB);     // [16,24)
    u16* x0h = (u16*)(wsp + 24 * MB); u16* x0l = (u16*)(wsp + 28 * MB);
    u16* yph = (u16*)(wsp + 32 * MB); u16* ypl = (u16*)(wsp + 36 * MB);
    u16* xph = (u16*)(wsp + 40 * MB); u16* xpl = (u16*)(wsp + 44 * MB);
    // scratch (liveness-overlapped)
    u16* qph = (u16*)(wsp + 56 * MB); u16* qpl = (u16*)(wsp + 60 * MB);
    u16* btWk_h = (u16*)(wsp + 48 * MB);
    u16* btWk_l = (u16*)(wsp + 48 * MB + 512 * 1024);
    u16* btWv_h = (u16*)(wsp + 49 * MB);
    u16* btWv_l = (u16*)(wsp + 49 * MB + 512 * 1024);
    u16* Vth = (u16*)(wsp + 48 * MB); u16* Vtl = (u16*)(wsp + 52 * MB);
    u16* btWo_h = (u16*)(wsp + 56 * MB);
    u16* btWo_l = (u16*)(wsp + 56 * MB + 512 * 1024);
    float* t1 = (float*)(wsp + 48 * MB);      // [48,56), after attn
    u16* btW1_h = (u16*)(wsp + 56 * MB); u16* btW1_l = (u16*)(wsp + 58 * MB);
    u16* btW2_h = (u16*)(wsp + 60 * MB); u16* btW2_l = (u16*)(wsp + 62 * MB);
    // head
    u16* hcath = (u16*)(wsp + 24 * MB); u16* hcatl = (u16*)(wsp + 32 * MB);
    u16* btH_h = (u16*)(wsp + 48 * MB); u16* btH_l = (u16*)(wsp + 50 * MB);
    u16* h1h = (u16*)(wsp + 56 * MB); u16* h1l = (u16*)(wsp + 60 * MB);
    u16* h2h = (u16*)(wsp);           u16* h2l = (u16*)(wsp + 8 * MB);

    embed_pp<<<dim3(TOK), dim3(256), 0, stream>>>(c_data, ca_data, c_emb, ca_emb,
                                                  x0b, yb, x0h, x0l, yph, ypl);

    for (int li = 0; li < 6; ++li) {
        const u16 *qsh, *qsl, *ksh, *ksl, *vsh, *vsl;
        const float* resid; float* outb; u16 *outph, *outpl;
        u16 *kph, *kpl, *vph, *vpl, *ffh, *ffl;
        int m0, pos;
        if (li == 0 || li == 1) {
            qsh = yph; qsl = ypl; ksh = x0h; ksl = x0l; vsh = yph; vsl = ypl;
            resid = yb; outb = yb; outph = yph; outpl = ypl; m0 = 0; pos = 1;
            kph = (u16*)(wsp + 16 * MB); kpl = (u16*)(wsp + 20 * MB);   // xb slot
            vph = (u16*)(wsp + 40 * MB); vpl = (u16*)(wsp + 44 * MB);   // xp slot
            ffh = (u16*)(wsp + 16 * MB); ffl = (u16*)(wsp + 40 * MB);
        } else if (li == 2) {
            qsh = x0h; qsl = x0l; ksh = x0h; ksl = x0l; vsh = x0h; vsl = x0l;
            resid = x0b; outb = xb; outph = xph; outpl = xpl; m0 = 0; pos = 0;
            kph = qph; kpl = qpl;
            vph = (u16*)(wsp + 16 * MB); vpl = (u16*)(wsp + 20 * MB);   // xb slot
            ffh = nullptr; ffl = nullptr;
        } else {
            int odd = (li == 3 || li == 5);
            qsh = xph; qsl = xpl; ksh = xph; ksl = xpl;
            if (odd) { vsh = yph; vsl = ypl; } else { vsh = xph; vsl = xpl; }
            resid = xb; outb = xb; outph = xph; outpl = xpl;
            m0 = odd ? 1 : 0; pos = odd ? 1 : 0;
            kph = qph; kpl = qpl;
            vph = (u16*)(wsp + 24 * MB); vpl = (u16*)(wsp + 28 * MB);   // x0p slot
            ffh = (u16*)(wsp + 8 * MB);  ffl = (u16*)(wsp + 24 * MB);   // yb + x0p slots
        }
        u16* aoph = vph; u16* aopl = vpl;   // vp dead after vtsplit

        wsplit2<<<dim3(8, 8, 2), dim3(256), 0, stream>>>(
            Wk + (size_t)li * DIM * DIM, Wv + (size_t)li * DIM * DIM,
            btWk_h, btWk_l, btWv_h, btWv_l);
        run_gemm(qsh, qsl, btWk_h, btWk_l, DIM, DIM, 0, bk + li * DIM, DIM, EP_PL,
                 nullptr, qph, qpl, stream);
        if (ksh != qsh) {
            run_gemm(ksh, ksl, btWk_h, btWk_l, DIM, DIM, 0, bk + li * DIM, DIM, EP_PL,
                     nullptr, kph, kpl, stream);
        }
        run_gemm(vsh, vsl, btWv_h, btWv_l, DIM, DIM, 0, bv + li * DIM, DIM, EP_PL,
                 nullptr, vph, vpl, stream);
        vtsplit_pp<<<dim3(SEQ / 64, BATCH * NHEAD), dim3(256), 0, stream>>>(vph, vpl, Vth, Vtl);
        attn_mf<<<dim3(16, NHEAD, BATCH), dim3(128), 0, stream>>>(
            qph, qpl, kph, kpl, Vth, Vtl, gammas + li * NHEAD, aoph, aopl, m0);
        run_wsplit(Wo + (size_t)li * DIM * DIM, btWo_h, btWo_l, DIM, DIM, DIM, stream);
        run_gemm(aoph, aopl, btWo_h, btWo_l, DIM, DIM, 0, bo + li * DIM, DIM, EP_F32,
                 t1, nullptr, nullptr, stream);
        add_ln_pp<<<dim3(TOK / 4), dim3(256), 0, stream>>>(resid, t1, ln1s + li * DIM,
                                                           ln1b + li * DIM, outb, outph, outpl);
        if (pos) {
            run_wsplit(W1 + (size_t)li * DIM * FFD, btW1_h, btW1_l, FFD, DIM, FFD, stream);
            run_wsplit(W2 + (size_t)li * FFD * DIM, btW2_h, btW2_l, DIM, FFD, DIM, stream);
            for (int c = 0; c < 2; ++c) {
                run_gemm(outph, outpl,
                         btW1_h + (size_t)c * 1024 * DIM, btW1_l + (size_t)c * 1024 * DIM,
                         DIM, DIM, 0, b1 + li * FFD + c * 1024, 1024, EP_RELU | EP_PL,
                         nullptr, ffh, ffl, stream);
                run_gemm(ffh, ffl, btW2_h, btW2_l, 1024, FFD, c * 1024,
                         b2 + li * DIM, DIM, (c == 0) ? EP_F32 : (EP_F32 | EP_ACC),
                         t1, nullptr, nullptr, stream);
            }
            add_ln_pp<<<dim3(TOK / 4), dim3(256), 0, stream>>>(outb, t1, ln2s + li * DIM,
                                                               ln2b + li * DIM, outb, outph, outpl);
        }
    }

    concat_pp<<<dim3(TOK), dim3(256), 0, stream>>>(xb, x0b, hcath, hcatl);
    run_wsplit(oW0, btH_h, btH_l, 512, 1024, 512, stream);
    run_gemm(hcath, hcatl, btH_h, btH_l, 1024, 1024, 0, ob0, 512, EP_RELU | EP_PL,
             nullptr, h1h, h1l, stream);
    run_wsplit(oW1, btH_h, btH_l, 1024, 512, 1024, stream);
    run_gemm(h1h, h1l, btH_h, btH_l, 512, 512, 0, ob1, 1024, EP_RELU | EP_PL,
             nullptr, h2h, h2l, stream);
    run_wsplit(oW2, btH_h, btH_l, 1000, 1024, 1024, stream);
    run_gemm(h2h, h2l, btH_h, btH_l, 1024, 1024, 0, ob2, 1000, EP_F32,
             out, nullptr, nullptr, stream);
}